// Round 13
// baseline (2195.990 us; speedup 1.0000x reference)
//
#include <hip/hip_runtime.h>
#include <hip/hip_bf16.h>
#include <math.h>

#define BB 4
#define NN 16384
#define KM 128
#define DD 128
#define HHD 8
#define LL 6
#define DFFN 512
#define NFF 16
#define DCC 64
#define MM 257
#define DHH 16
#define SKC 32      // split-K chunks for slice
#define TPAD 320    // t-dim padded

typedef __hip_bfloat16 bf16;
using bf16x8 = __attribute__((ext_vector_type(8))) short;
using f32x4  = __attribute__((ext_vector_type(4))) float;

__device__ __forceinline__ void split2(float v, bf16& hi, bf16& lo) {
  hi = __float2bfloat16(v);
  lo = __float2bfloat16(v - __bfloat162float(hi));
}
__device__ __forceinline__ short b2s(bf16 x) {
  union { bf16 b; short s; } u; u.b = x; return u.s;
}

// ---------------- prep: bf16 hi/lo transposed FFN weights ----------------
__global__ void k_prepW(const float* __restrict__ f1_w, const float* __restrict__ f2_w,
                        bf16* __restrict__ f1T_hi, bf16* __restrict__ f1T_lo,
                        bf16* __restrict__ f2T_hi, bf16* __restrict__ f2T_lo) {
  size_t i = (size_t)blockIdx.x * 256 + threadIdx.x;
  size_t n = (size_t)LL * DFFN * DD;
  if (i < n) {
    int l = i / (DFFN * DD); int rem = i % (DFFN * DD); int f = rem / DD; int d = rem % DD;
    bf16 hi, lo; split2(f1_w[(size_t)l * DD * DFFN + (size_t)d * DFFN + f], hi, lo);
    f1T_hi[i] = hi; f1T_lo[i] = lo;
  } else if (i < 2 * n) {
    size_t j = i - n;
    int l = j / (DD * DFFN); int rem = j % (DD * DFFN); int d = rem / DFFN; int f = rem % DFFN;
    bf16 hi, lo; split2(f2_w[(size_t)l * DFFN * DD + (size_t)f * DD + d], hi, lo);
    f2T_hi[j] = hi; f2T_lo[j] = lo;
  }
}

// ------- embed v3: 32 pts/block, 2 pts x 128 d per iter, weights in LDS -------
__global__ void __launch_bounds__(256)
k_embed(const float* __restrict__ u, const float* __restrict__ nodes,
        const float* __restrict__ coordB,
        const float* __restrict__ cp_w, const float* __restrict__ cp_b,
        const float* __restrict__ in_w, const float* __restrict__ in_b,
        float* __restrict__ h) {
  int p0 = blockIdx.x * 32;
  int tid = threadIdx.x;
  int half = tid >> 7, d = tid & 127;
  __shared__ float w_in[66][128];   // 33.8 KB
  __shared__ float w_cp[34][64];    // 8.7 KB
  __shared__ float feats[2][34];
  __shared__ float hin[2][66];
  for (int i = tid; i < 66 * 128; i += 256) w_in[i >> 7][i & 127] = in_w[i];
  for (int i = tid; i < 34 * 64; i += 256) w_cp[i >> 6][i & 63] = cp_w[i];
  __syncthreads();
  for (int pp = 0; pp < 32; pp += 2) {
    int p = p0 + pp + half;
    if (d < 16) {
      float n0 = nodes[(size_t)p * 2 + 0], n1 = nodes[(size_t)p * 2 + 1];
      float xb = n0 * coordB[d] + n1 * coordB[NFF + d];
      feats[half][2 + d] = sinf(xb);
      feats[half][2 + NFF + d] = cosf(xb);
      if (d < 2) feats[half][d] = nodes[(size_t)p * 2 + d];
      if (d >= 2 && d < 4) hin[half][d - 2] = u[(size_t)p * 2 + d - 2];
    }
    __syncthreads();
    if (d < 64) {
      float acc = cp_b[d];
      #pragma unroll
      for (int i = 0; i < 34; ++i) acc += feats[half][i] * w_cp[i][d];
      hin[half][2 + d] = acc;
    }
    __syncthreads();
    float acc = in_b[d];
    #pragma unroll
    for (int i = 0; i < 66; ++i) acc += hin[half][i] * w_in[i][d];
    h[(size_t)p * DD + d] = acc;
    __syncthreads();
  }
}

__device__ __forceinline__ float basis_val(int t, float n0, float n1, const float* modes) {
  if (t >= 2 * KM) return (t == 2 * KM) ? 1.0f : 0.0f;
  int mi = t & (KM - 1);
  float th = n0 * modes[mi * 2 + 0] + n1 * modes[mi * 2 + 1];
  float s, c; __sincosf(th, &s, &c);
  return (t < KM) ? c : s;
}

// ---------------- basesT [b][t][x] single bf16 (slice B operand) ----------------
__global__ void k_basesT(const float* __restrict__ nodes, const float* __restrict__ modes,
                         bf16* __restrict__ bT) {
  int t = blockIdx.y, b = blockIdx.z;
  int x = blockIdx.x * 256 + threadIdx.x;
  float2 nd = *(const float2*)(nodes + ((size_t)b * NN + x) * 2);
  float v = basis_val(t, nd.x, nd.y, modes);
  bT[((size_t)b * TPAD + t) * NN + x] = __float2bfloat16(v);
}

// ---------------- basesR [b][x][t] single bf16 (deslice A operand) ----------------
__global__ void k_basesR(const float* __restrict__ nodes, const float* __restrict__ modes,
                         bf16* __restrict__ bR) {
  int p = blockIdx.x;          // b*N + x
  int t = threadIdx.x;         // 0..319
  float2 nd = *(const float2*)(nodes + (size_t)p * 2);
  float v = basis_val(t, nd.x, nd.y, modes);
  bR[(size_t)p * TPAD + t] = __float2bfloat16(v);
}

// ---------------- one-time: zero the Zt pad columns ----------------
__global__ void k_ztpad(bf16* __restrict__ Zt_hi, bf16* __restrict__ Zt_lo) {
  int i = blockIdx.x * 256 + threadIdx.x;
  int tot = BB * DD * (TPAD - MM);
  if (i >= tot) return;
  int bd = i / (TPAD - MM); int t = MM + i % (TPAD - MM);
  size_t idx = (size_t)bd * TPAD + t;
  Zt_hi[idx] = __float2bfloat16(0.f);
  Zt_lo[idx] = __float2bfloat16(0.f);
}

// ---------------- hTw init: [d][x] = h*w, hi/lo ----------------
__global__ void k_hTw(const float* __restrict__ h, const float* __restrict__ nw,
                      bf16* __restrict__ hw_hi, bf16* __restrict__ hw_lo) {
  int xt = blockIdx.x, b = blockIdx.y; int x0 = xt * 64;
  __shared__ float T[128][67];
  __shared__ float wls[64];
  int tid = threadIdx.x;
  if (tid < 64) wls[tid] = nw[(size_t)b * NN + x0 + tid];
  for (int it = 0; it < 32; ++it) {
    int eid = it * 256 + tid; int x = eid >> 7, d = eid & 127;
    T[d][x] = h[((size_t)b * NN + x0 + x) * DD + d];
  }
  __syncthreads();
  for (int it = 0; it < 32; ++it) {
    int eid = it * 256 + tid; int d = eid >> 6, xl = eid & 63;
    float v = T[d][xl] * wls[xl];
    bf16 hi, lo; split2(v, hi, lo);
    size_t idx = ((size_t)b * DD + d) * NN + x0 + xl;
    hw_hi[idx] = hi; hw_lo[idx] = lo;
  }
}

// ---------------- slice (MFMA, no LDS): partialT[b][ck][d][t] ----------------
__global__ void __launch_bounds__(256, 4)
k_slice(const bf16* __restrict__ bT, const bf16* __restrict__ hw_hi,
        const bf16* __restrict__ hw_lo, float* __restrict__ partialT) {
  int ck = blockIdx.x, tg = blockIdx.y, b = blockIdx.z;
  int kbase = ck * (NN / SKC);   // 512-chunk of x
  int tid = threadIdx.x, w = tid >> 6, lane = tid & 63, lr = lane & 15, lg = lane >> 4;
  const bf16* pAh = hw_hi + ((size_t)b * DD + w * 32 + lr) * NN + kbase + lg * 8;
  const bf16* pAl = hw_lo + ((size_t)b * DD + w * 32 + lr) * NN + kbase + lg * 8;
  const bf16* pB  = bT + ((size_t)b * TPAD + tg * 64 + lr) * NN + kbase + lg * 8;
  f32x4 acc[8];
  #pragma unroll
  for (int i = 0; i < 8; i++) acc[i] = (f32x4){0.f, 0.f, 0.f, 0.f};
  for (int kc = 0; kc < NN / SKC; kc += 64) {
    bf16x8 ah[2][2], al[2][2], bb[2][4];
    #pragma unroll
    for (int ks2 = 0; ks2 < 2; ++ks2) {
      int ko = kc + ks2 * 32;
      #pragma unroll
      for (int fi = 0; fi < 2; ++fi) {
        ah[ks2][fi] = *(const bf16x8*)(pAh + (size_t)fi * 16 * NN + ko);
        al[ks2][fi] = *(const bf16x8*)(pAl + (size_t)fi * 16 * NN + ko);
      }
      #pragma unroll
      for (int tc = 0; tc < 4; ++tc)
        bb[ks2][tc] = *(const bf16x8*)(pB + (size_t)tc * 16 * NN + ko);
    }
    #pragma unroll
    for (int ks2 = 0; ks2 < 2; ++ks2)
      #pragma unroll
      for (int fi = 0; fi < 2; ++fi)
        #pragma unroll
        for (int tc = 0; tc < 4; ++tc) {
          int ai = fi * 4 + tc;
          acc[ai] = __builtin_amdgcn_mfma_f32_16x16x32_bf16(ah[ks2][fi], bb[ks2][tc], acc[ai], 0, 0, 0);
          acc[ai] = __builtin_amdgcn_mfma_f32_16x16x32_bf16(al[ks2][fi], bb[ks2][tc], acc[ai], 0, 0, 0);
        }
  }
  float* pp = partialT + ((size_t)(b * SKC + ck) * DD) * TPAD;
  #pragma unroll
  for (int fi = 0; fi < 2; ++fi)
    #pragma unroll
    for (int tc = 0; tc < 4; ++tc)
      #pragma unroll
      for (int r = 0; r < 4; ++r) {
        int d = w * 32 + fi * 16 + lg * 4 + r;
        int t = tg * 64 + tc * 16 + lr;
        pp[(size_t)d * TPAD + t] = acc[fi * 4 + tc][r];
      }
}

// ------- qkv (fused reduce + LN1): reads partialT, writes Z,q,k,v -------
__global__ void k_qkv(const float* __restrict__ partialT, const float* __restrict__ lnw,
                      const float* __restrict__ lnb, const float* __restrict__ W,
                      const float* __restrict__ bias, float* __restrict__ Z,
                      float* __restrict__ q, float* __restrict__ k, float* __restrict__ v) {
  int row = blockIdx.x;            // b*M + t
  int b = row / MM, t = row % MM;
  int j = threadIdx.x;             // 0..383
  __shared__ float zr[128];
  __shared__ float red[4];
  if (j < 128) {
    float s0 = 0.f;
    #pragma unroll
    for (int ck = 0; ck < SKC; ++ck)
      s0 += partialT[((size_t)(b * SKC + ck) * DD + j) * TPAD + t];
    Z[(size_t)row * DD + j] = s0;
    zr[j] = s0;
    float s = s0, q2 = s0 * s0;
    for (int off = 32; off; off >>= 1) { s += __shfl_xor(s, off); q2 += __shfl_xor(q2, off); }
    if ((j & 63) == 0) { red[(j >> 6) * 2] = s; red[(j >> 6) * 2 + 1] = q2; }
  }
  __syncthreads();
  float s = red[0] + red[2], q2 = red[1] + red[3];
  float mean = s / 128.f;
  float var = q2 / 128.f - mean * mean;
  float inv = rsqrtf(var + 1e-5f);
  if (j < 128) zr[j] = (zr[j] - mean) * inv * lnw[j] + lnb[j];
  __syncthreads();
  float acc = bias[j];
  for (int i = 0; i < 128; i++) acc += zr[i] * W[(size_t)i * 384 + j];
  int which = j >> 7;
  int jj = j & 127;
  int hh = jj >> 4, dh = jj & 15;
  float* dst = (which == 0) ? q : (which == 1) ? k : v;
  dst[((size_t)(b * HHD + hh) * MM + t) * DHH + dh] = acc;
}

// ---------------- attention (split-KV, 8 segs/row, shfl merge) ----------------
__global__ void __launch_bounds__(256, 4)
k_att(const float* __restrict__ q, const float* __restrict__ k,
      const float* __restrict__ v, float* __restrict__ obuf) {
  int bh = blockIdx.y; int b = bh / HHD, hh = bh % HHD;
  int rt = blockIdx.x;             // 0..8, rows rt*32 .. rt*32+31
  __shared__ float ks[MM * DHH];
  __shared__ float vs[MM * DHH];
  const float* kp = k + (size_t)bh * MM * DHH;
  const float* vp = v + (size_t)bh * MM * DHH;
  for (int i = threadIdx.x; i < MM * DHH; i += 256) { ks[i] = kp[i]; vs[i] = vp[i]; }
  __syncthreads();
  const float scale = 0.25f;
  int tid = threadIdx.x;
  int row = rt * 32 + (tid >> 3);
  int seg = tid & 7;
  float m = -1e30f, s = 0.f, o[16];
  #pragma unroll
  for (int j = 0; j < 16; j++) o[j] = 0.f;
  if (row < MM) {
    float qr[16];
    const float* qp = q + ((size_t)bh * MM + row) * DHH;
    #pragma unroll
    for (int j = 0; j < 16; j++) qr[j] = qp[j];
    int t0 = seg * 33;
    int t1 = t0 + 33; if (t1 > MM) t1 = MM;
    for (int t = t0; t < t1; t++) {
      float sc = 0.f;
      #pragma unroll
      for (int j = 0; j < 16; j++) sc += qr[j] * ks[t * 16 + j];
      sc *= scale;
      float mn = fmaxf(m, sc);
      float corr = __expf(m - mn);
      float e = __expf(sc - mn);
      s = s * corr + e;
      #pragma unroll
      for (int j = 0; j < 16; j++) o[j] = o[j] * corr + e * vs[t * 16 + j];
      m = mn;
    }
  }
  #pragma unroll
  for (int off2 = 1; off2 < 8; off2 <<= 1) {
    float m2 = __shfl_xor(m, off2);
    float s2 = __shfl_xor(s, off2);
    float mn = fmaxf(m, m2);
    float c1 = __expf(m - mn), c2 = __expf(m2 - mn);
    s = s * c1 + s2 * c2;
    #pragma unroll
    for (int j = 0; j < 16; j++) o[j] = o[j] * c1 + __shfl_xor(o[j], off2) * c2;
    m = mn;
  }
  if (seg == 0 && row < MM) {
    float invs = 1.f / s;
    float* op = obuf + ((size_t)(b * MM + row)) * DD + hh * DHH;
    #pragma unroll
    for (int j4 = 0; j4 < 4; ++j4) {
      float4 vv = make_float4(o[j4 * 4] * invs, o[j4 * 4 + 1] * invs,
                              o[j4 * 4 + 2] * invs, o[j4 * 4 + 3] * invs);
      *(float4*)(op + j4 * 4) = vv;
    }
  }
}

// ---------------- attn out proj -> Zt hi/lo directly (fused zt) ----------------
__global__ void k_ao(const float* __restrict__ obuf, const float* __restrict__ W,
                     const float* __restrict__ bias, const float* __restrict__ Z,
                     bf16* __restrict__ Zt_hi, bf16* __restrict__ Zt_lo) {
  int row = blockIdx.x; int d = threadIdx.x;
  int b = row / MM, t = row % MM;
  __shared__ float orow[128];
  orow[d] = obuf[(size_t)row * DD + d];
  __syncthreads();
  float acc = bias[d];
  for (int i = 0; i < 128; i++) acc += orow[i] * W[(size_t)i * DD + d];
  float nz = Z[(size_t)row * DD + d] + acc;
  bf16 hi, lo; split2(nz, hi, lo);
  size_t idx = ((size_t)b * DD + d) * TPAD + t;
  Zt_hi[idx] = hi; Zt_lo[idx] = lo;
}

// ------- deslice (MFMA, pure global like slice) + fused LN2 -> ln2h bf16 -------
__global__ void __launch_bounds__(256, 4)
k_deslice(const bf16* __restrict__ bR, const bf16* __restrict__ Zt_hi,
          const bf16* __restrict__ Zt_lo, const float* __restrict__ lw,
          const float* __restrict__ lb, float* __restrict__ h,
          bf16* __restrict__ ln2h) {
  int xt = blockIdx.x, b = blockIdx.y;
  int x0 = xt * 64;
  int tid = threadIdx.x, w = tid >> 6, lane = tid & 63, lr = lane & 15, lg = lane >> 4;
  const bf16* pA  = bR + ((size_t)b * NN + x0 + w * 16 + lr) * TPAD + lg * 8;
  const bf16* pBh = Zt_hi + ((size_t)b * DD + lr) * TPAD + lg * 8;
  const bf16* pBl = Zt_lo + ((size_t)b * DD + lr) * TPAD + lg * 8;
  f32x4 acc[8];
  #pragma unroll
  for (int i = 0; i < 8; i++) acc[i] = (f32x4){0.f, 0.f, 0.f, 0.f};
  for (int kc = 0; kc < TPAD; kc += 64) {
    #pragma unroll
    for (int ks2 = 0; ks2 < 2; ++ks2) {
      int ko = kc + ks2 * 32;
      bf16x8 a = *(const bf16x8*)(pA + ko);
      #pragma unroll
      for (int fg = 0; fg < 2; ++fg) {
        bf16x8 bh[4], bl[4];
        #pragma unroll
        for (int fj = 0; fj < 4; ++fj) {
          int fi = fg * 4 + fj;
          bh[fj] = *(const bf16x8*)(pBh + (size_t)fi * 16 * TPAD + ko);
          bl[fj] = *(const bf16x8*)(pBl + (size_t)fi * 16 * TPAD + ko);
        }
        #pragma unroll
        for (int fj = 0; fj < 4; ++fj) {
          int fi = fg * 4 + fj;
          acc[fi] = __builtin_amdgcn_mfma_f32_16x16x32_bf16(a, bh[fj], acc[fi], 0, 0, 0);
          acc[fi] = __builtin_amdgcn_mfma_f32_16x16x32_bf16(a, bl[fj], acc[fi], 0, 0, 0);
        }
      }
    }
  }
  float lwv[8], lbv[8];
  #pragma unroll
  for (int fi = 0; fi < 8; ++fi) { lwv[fi] = lw[fi * 16 + lr]; lbv[fi] = lb[fi * 16 + lr]; }
  float hv[8][4];
  float sm[4], sq[4];
  #pragma unroll
  for (int r = 0; r < 4; ++r) { sm[r] = 0.f; sq[r] = 0.f; }
  size_t rowbase = ((size_t)b * NN + x0 + w * 16 + lg * 4);
  #pragma unroll
  for (int fi = 0; fi < 8; ++fi)
    #pragma unroll
    for (int r = 0; r < 4; ++r) {
      float v = h[(rowbase + r) * DD + fi * 16 + lr] + acc[fi][r];
      hv[fi][r] = v; sm[r] += v; sq[r] += v * v;
    }
  #pragma unroll
  for (int r = 0; r < 4; ++r) {
    float s = sm[r], q = sq[r];
    s += __shfl_xor(s, 1); q += __shfl_xor(q, 1);
    s += __shfl_xor(s, 2); q += __shfl_xor(q, 2);
    s += __shfl_xor(s, 4); q += __shfl_xor(q, 4);
    s += __shfl_xor(s, 8); q += __shfl_xor(q, 8);
    float mean = s / 128.f;
    float var = q / 128.f - mean * mean;
    sm[r] = mean; sq[r] = rsqrtf(var + 1e-5f);
  }
  #pragma unroll
  for (int fi = 0; fi < 8; ++fi)
    #pragma unroll
    for (int r = 0; r < 4; ++r) {
      float v = hv[fi][r];
      h[(rowbase + r) * DD + fi * 16 + lr] = v;
      float ln = (v - sm[r]) * sq[r] * lwv[fi] + lbv[fi];
      ln2h[(rowbase + r) * DD + fi * 16 + lr] = __float2bfloat16(ln);
    }
}

// ------- ffnA (MFMA, 64-row blocks): mid = gelu(ln2h @ f1 + b1) bf16 -------
__global__ void __launch_bounds__(256, 2)
k_ffnA(const bf16* __restrict__ ln2h, const bf16* __restrict__ f1T_hi,
       const bf16* __restrict__ f1T_lo, const float* __restrict__ b1,
       bf16* __restrict__ mid) {
  int x0 = blockIdx.x * 64;
  int tid = threadIdx.x, w = tid >> 6, lane = tid & 63, lr = lane & 15, lg = lane >> 4;
  int f0 = w * 128;
  __shared__ short mid_s[16][DFFN + 8];
  f32x4 acc[4][8];
  #pragma unroll
  for (int rt = 0; rt < 4; ++rt)
    #pragma unroll
    for (int fi = 0; fi < 8; ++fi) acc[rt][fi] = (f32x4){0.f, 0.f, 0.f, 0.f};
  #pragma unroll
  for (int ks = 0; ks < 4; ++ks) {
    bf16x8 a[4];
    #pragma unroll
    for (int rt = 0; rt < 4; ++rt)
      a[rt] = *(const bf16x8*)(ln2h + ((size_t)x0 + rt * 16 + lr) * DD + ks * 32 + lg * 8);
    bf16x8 bh[8];
    #pragma unroll
    for (int fi = 0; fi < 8; ++fi)
      bh[fi] = *(const bf16x8*)(f1T_hi + (size_t)(f0 + fi * 16 + lr) * DD + ks * 32 + lg * 8);
    #pragma unroll
    for (int fi = 0; fi < 8; ++fi)
      #pragma unroll
      for (int rt = 0; rt < 4; ++rt)
        acc[rt][fi] = __builtin_amdgcn_mfma_f32_16x16x32_bf16(a[rt], bh[fi], acc[rt][fi], 0, 0, 0);
    bf16x8 bl[8];
    #pragma unroll
    for (int fi = 0; fi < 8; ++fi)
      bl[fi] = *(const bf16x8*)(f1T_lo + (size_t)(f0 + fi * 16 + lr) * DD + ks * 32 + lg * 8);
    #pragma unroll
    for (int fi = 0; fi < 8; ++fi)
      #pragma unroll
      for (int rt = 0; rt < 4; ++rt)
        acc[rt][fi] = __builtin_amdgcn_mfma_f32_16x16x32_bf16(a[rt], bl[fi], acc[rt][fi], 0, 0, 0);
  }
  #pragma unroll
  for (int rt = 0; rt < 4; ++rt) {
    __syncthreads();
    #pragma unroll
    for (int fi = 0; fi < 8; ++fi) {
      int col = f0 + fi * 16 + lr;
      float bb = b1[col];
      #pragma unroll
      for (int r = 0; r < 4; ++r) {
        float xx = acc[rt][fi][r] + bb;
        float gl = 0.5f * xx * (1.f + erff(xx * 0.70710678118654752f));
        mid_s[lg * 4 + r][col] = b2s(__float2bfloat16(gl));
      }
    }
    __syncthreads();
    #pragma unroll
    for (int it = 0; it < 4; ++it) {
      int eid = it * 256 + tid;
      int row = eid >> 6, c = eid & 63;
      uint4 vv = *(const uint4*)&mid_s[row][c * 8];
      *(uint4*)(mid + ((size_t)x0 + rt * 16 + row) * DFFN + c * 8) = vv;
    }
  }
}

// ------- ffnB (MFMA): wave owns 32 d-cols x all 64 rows; h += mid@f2 + b2 -------
__global__ void __launch_bounds__(256, 2)
k_ffnB(const bf16* __restrict__ mid, const bf16* __restrict__ f2T_hi,
       const bf16* __restrict__ f2T_lo, const float* __restrict__ b2,
       const float* __restrict__ nw, float* __restrict__ h,
       bf16* __restrict__ hw_hi, bf16* __restrict__ hw_lo) {
  int x0 = blockIdx.x * 64;
  int b = x0 / NN; int xb = x0 % NN;
  int tid = threadIdx.x, w = tid >> 6, lane = tid & 63, lr = lane & 15, lg = lane >> 4;
  int d0 = w * 32;
  __shared__ float T[128][67];
  __shared__ float wls[64];
  if (tid < 64) wls[tid] = nw[(size_t)b * NN + xb + tid];
  f32x4 acc[4][2];
  #pragma unroll
  for (int rt = 0; rt < 4; ++rt)
    #pragma unroll
    for (int dj = 0; dj < 2; ++dj) acc[rt][dj] = (f32x4){0.f, 0.f, 0.f, 0.f};
  #pragma unroll
  for (int ks = 0; ks < 16; ++ks) {
    bf16x8 a[4];
    #pragma unroll
    for (int rt = 0; rt < 4; ++rt)
      a[rt] = *(const bf16x8*)(mid + ((size_t)x0 + rt * 16 + lr) * DFFN + ks * 32 + lg * 8);
    bf16x8 bh[2], bl[2];
    #pragma unroll
    for (int dj = 0; dj < 2; ++dj) {
      size_t widx = (size_t)(d0 + dj * 16 + lr) * DFFN + ks * 32 + lg * 8;
      bh[dj] = *(const bf16x8*)(f2T_hi + widx);
      bl[dj] = *(const bf16x8*)(f2T_lo + widx);
    }
    #pragma unroll
    for (int dj = 0; dj < 2; ++dj)
      #pragma unroll
      for (int rt = 0; rt < 4; ++rt) {
        acc[rt][dj] = __builtin_amdgcn_mfma_f32_16x16x32_bf16(a[rt], bh[dj], acc[rt][dj], 0, 0, 0);
        acc[rt][dj] = __builtin_amdgcn_mfma_f32_16x16x32_bf16(a[rt], bl[dj], acc[rt][dj], 0, 0, 0);
      }
  }
  #pragma unroll
  for (int dj = 0; dj < 2; ++dj) {
    int d = d0 + dj * 16 + lr;
    float bb = b2[d];
    #pragma unroll
    for (int rt = 0; rt < 4; ++rt)
      #pragma unroll
      for (int r = 0; r < 4; ++r) {
        int rowl = rt * 16 + lg * 4 + r;
        float v = h[((size_t)x0 + rowl) * DD + d] + acc[rt][dj][r] + bb;
        h[((size_t)x0 + rowl) * DD + d] = v;
        T[d][rowl] = v;
      }
  }
  __syncthreads();
  for (int it = 0; it < 32; ++it) {
    int eid = it * 256 + tid; int d = eid >> 6, xl = eid & 63;
    float v = T[d][xl] * wls[xl];
    bf16 hi, lo; split2(v, hi, lo);
    size_t idx = ((size_t)b * DD + d) * NN + xb + xl;
    hw_hi[idx] = hi; hw_lo[idx] = lo;
  }
}

// ---------------- final LN + out proj (f32 out) ----------------
__global__ void k_out(const float* __restrict__ h, const float* __restrict__ lw,
                      const float* __restrict__ lb, const float* __restrict__ ow,
                      const float* __restrict__ ob, float* __restrict__ out) {
  int row = blockIdx.x; int tid = threadIdx.x;
  float v = h[(size_t)row * DD + tid];
  float s = v, q = v * v;
  for (int off = 32; off; off >>= 1) { s += __shfl_xor(s, off); q += __shfl_xor(q, off); }
  __shared__ float sh[4];
  __shared__ float sp[4];
  int wv = tid >> 6;
  if ((tid & 63) == 0) { sh[wv] = s; sh[2 + wv] = q; }
  __syncthreads();
  s = sh[0] + sh[1]; q = sh[2] + sh[3];
  float mean = s / 128.f, var = q / 128.f - mean * mean;
  float inv = rsqrtf(var + 1e-5f);
  float ln = (v - mean) * inv * lw[tid] + lb[tid];
  float p0 = ln * ow[tid * 2 + 0], p1 = ln * ow[tid * 2 + 1];
  for (int off = 32; off; off >>= 1) { p0 += __shfl_xor(p0, off); p1 += __shfl_xor(p1, off); }
  if ((tid & 63) == 0) { sp[wv] = p0; sp[2 + wv] = p1; }
  __syncthreads();
  if (tid == 0) out[(size_t)row * 2 + 0] = sp[0] + sp[1] + ob[0];
  if (tid == 1) out[(size_t)row * 2 + 1] = sp[2] + sp[3] + ob[1];
}

extern "C" void kernel_launch(void* const* d_in, const int* in_sizes, int n_in,
                              void* d_out, int out_size, void* d_ws, size_t ws_size,
                              hipStream_t stream) {
  const float* u      = (const float*)d_in[0];
  const float* nodes  = (const float*)d_in[1];
  const float* nw     = (const float*)d_in[2];
  const float* modes  = (const float*)d_in[3];
  const float* coordB = (const float*)d_in[4];
  const float* cp_w   = (const float*)d_in[5];
  const float* cp_b   = (const float*)d_in[6];
  const float* in_w   = (const float*)d_in[7];
  const float* in_b   = (const float*)d_in[8];
  const float* ln1_w  = (const float*)d_in[9];
  const float* ln1_b  = (const float*)d_in[10];
  const float* qkv_w  = (const float*)d_in[11];
  const float* qkv_b  = (const float*)d_in[12];
  const float* ao_w   = (const float*)d_in[13];
  const float* ao_b   = (const float*)d_in[14];
  const float* f1_w   = (const float*)d_in[15];
  const float* f1_b   = (const float*)d_in[16];
  const float* f2_w   = (const float*)d_in[17];
  const float* f2_b   = (const float*)d_in[18];
  const float* ln2_w  = (const float*)d_in[19];
  const float* ln2_b  = (const float*)d_in[20];
  const float* lnf_w  = (const float*)d_in[21];
  const float* lnf_b  = (const float*)d_in[22];
  const float* out_w  = (const float*)d_in[23];
  const float* out_b  = (const float*)d_in[24];

  char* ws = (char*)d_ws;
  size_t off = 0;
  bf16* bT    = (bf16*)(ws + off); off += (size_t)BB * TPAD * NN * 2;   // 41.9 MB
  bf16* bR    = (bf16*)(ws + off); off += (size_t)BB * NN * TPAD * 2;   // 41.9 MB
  float* h    = (float*)(ws + off); off += (size_t)BB * NN * DD * 4;    // 33.6 MB
  bf16* hw_hi = (bf16*)(ws + off); off += (size_t)BB * DD * NN * 2;     // 16.8 MB
  bf16* hw_lo = (bf16*)(ws + off); off += (size_t)BB * DD * NN * 2;     // 16.8 MB
  bf16* ln2h  = (bf16*)(ws + off); off += (size_t)BB * NN * DD * 2;     // 16.8 MB
  char* regMid = ws + off; off += (size_t)BB * NN * DFFN * 2;           // 67.1 MB
  float* partialT = (float*)regMid;                       // live: slice -> qkv
  bf16*  mid      = (bf16*)regMid;                        // live: ffnA -> ffnB
  float* qb  = (float*)(regMid + 40 * 1024 * 1024);       // live: qkv -> att
  float* kb  = qb  + (size_t)BB * MM * DD;
  float* vb  = kb  + (size_t)BB * MM * DD;
  float* ob2 = vb  + (size_t)BB * MM * DD;                // live: att -> ao
  float* Z    = (float*)(ws + off); off += (size_t)BB * MM * DD * 4;
  bf16* Zt_hi = (bf16*)(ws + off); off += (size_t)BB * DD * TPAD * 2;
  bf16* Zt_lo = (bf16*)(ws + off); off += (size_t)BB * DD * TPAD * 2;
  bf16* f1T_hi = (bf16*)(ws + off); off += (size_t)LL * DFFN * DD * 2;
  bf16* f1T_lo = (bf16*)(ws + off); off += (size_t)LL * DFFN * DD * 2;
  bf16* f2T_hi = (bf16*)(ws + off); off += (size_t)LL * DD * DFFN * 2;
  bf16* f2T_lo = (bf16*)(ws + off); off += (size_t)LL * DD * DFFN * 2;
  // total ~239.2 MB

  k_prepW<<<(2 * LL * DFFN * DD + 255) / 256, 256, 0, stream>>>(f1_w, f2_w, f1T_hi, f1T_lo, f2T_hi, f2T_lo);
  k_embed<<<BB * NN / 32, 256, 0, stream>>>(u, nodes, coordB, cp_w, cp_b, in_w, in_b, h);
  k_basesT<<<dim3(NN / 256, TPAD, BB), 256, 0, stream>>>(nodes, modes, bT);
  k_basesR<<<BB * NN, TPAD, 0, stream>>>(nodes, modes, bR);
  k_hTw<<<dim3(NN / 64, BB), 256, 0, stream>>>(h, nw, hw_hi, hw_lo);
  k_ztpad<<<(BB * DD * (TPAD - MM) + 255) / 256, 256, 0, stream>>>(Zt_hi, Zt_lo);

  for (int l = 0; l < LL; l++) {
    k_slice<<<dim3(SKC, TPAD / 64, BB), 256, 0, stream>>>(bT, hw_hi, hw_lo, partialT);
    k_qkv<<<BB * MM, 384, 0, stream>>>(partialT, ln1_w + l * DD, ln1_b + l * DD,
                                       qkv_w + (size_t)l * DD * 3 * DD, qkv_b + l * 3 * DD,
                                       Z, qb, kb, vb);
    k_att<<<dim3(9, BB * HHD), 256, 0, stream>>>(qb, kb, vb, ob2);
    k_ao<<<BB * MM, 128, 0, stream>>>(ob2, ao_w + (size_t)l * DD * DD, ao_b + l * DD, Z, Zt_hi, Zt_lo);
    k_deslice<<<dim3(NN / 64, BB), 256, 0, stream>>>(bR, Zt_hi, Zt_lo,
                                                     ln2_w + l * DD, ln2_b + l * DD, h, ln2h);
    k_ffnA<<<BB * NN / 64, 256, 0, stream>>>(ln2h, f1T_hi + (size_t)l * DFFN * DD,
                                             f1T_lo + (size_t)l * DFFN * DD, f1_b + l * DFFN, mid);
    k_ffnB<<<BB * NN / 64, 256, 0, stream>>>(mid, f2T_hi + (size_t)l * DD * DFFN,
                                             f2T_lo + (size_t)l * DD * DFFN, f2_b + l * DD,
                                             nw, h, hw_hi, hw_lo);
  }
  k_out<<<BB * NN, 128, 0, stream>>>(h, lnf_w, lnf_b, out_w, out_b, (float*)d_out);
}

// Round 14
// 2015.088 us; speedup vs baseline: 1.0898x; 1.0898x over previous
//
#include <hip/hip_runtime.h>
#include <hip/hip_bf16.h>
#include <math.h>

#define BB 4
#define NN 16384
#define KM 128
#define DD 128
#define HHD 8
#define LL 6
#define DFFN 512
#define NFF 16
#define DCC 64
#define MM 257
#define DHH 16
#define SKC 32      // split-K chunks for slice
#define TPAD 320    // t-dim padded

typedef __hip_bfloat16 bf16;
using bf16x8 = __attribute__((ext_vector_type(8))) short;
using f32x4  = __attribute__((ext_vector_type(4))) float;

__device__ __forceinline__ void split2(float v, bf16& hi, bf16& lo) {
  hi = __float2bfloat16(v);
  lo = __float2bfloat16(v - __bfloat162float(hi));
}
__device__ __forceinline__ short b2s(bf16 x) {
  union { bf16 b; short s; } u; u.b = x; return u.s;
}

// ---------------- prep: bf16 hi/lo transposed FFN weights ----------------
__global__ void k_prepW(const float* __restrict__ f1_w, const float* __restrict__ f2_w,
                        bf16* __restrict__ f1T_hi, bf16* __restrict__ f1T_lo,
                        bf16* __restrict__ f2T_hi, bf16* __restrict__ f2T_lo) {
  size_t i = (size_t)blockIdx.x * 256 + threadIdx.x;
  size_t n = (size_t)LL * DFFN * DD;
  if (i < n) {
    int l = i / (DFFN * DD); int rem = i % (DFFN * DD); int f = rem / DD; int d = rem % DD;
    bf16 hi, lo; split2(f1_w[(size_t)l * DD * DFFN + (size_t)d * DFFN + f], hi, lo);
    f1T_hi[i] = hi; f1T_lo[i] = lo;
  } else if (i < 2 * n) {
    size_t j = i - n;
    int l = j / (DD * DFFN); int rem = j % (DD * DFFN); int d = rem / DFFN; int f = rem % DFFN;
    bf16 hi, lo; split2(f2_w[(size_t)l * DFFN * DD + (size_t)f * DD + d], hi, lo);
    f2T_hi[j] = hi; f2T_lo[j] = lo;
  }
}

// ------- embed v4: 64 pts/block, weights+feats+hin in LDS, 3 barriers -------
__global__ void __launch_bounds__(256)
k_embed(const float* __restrict__ u, const float* __restrict__ nodes,
        const float* __restrict__ coordB,
        const float* __restrict__ cp_w, const float* __restrict__ cp_b,
        const float* __restrict__ in_w, const float* __restrict__ in_b,
        float* __restrict__ h) {
  int p0 = blockIdx.x * 64;
  int tid = threadIdx.x;
  __shared__ float w_in[66][128];   // 33.8 KB
  __shared__ float w_cp[34][64];    // 8.7 KB
  __shared__ float feats[64][34];   // 8.7 KB
  __shared__ float hin[64][68];     // 17.4 KB
  for (int i = tid; i < 66 * 128; i += 256) w_in[i >> 7][i & 127] = in_w[i];
  for (int i = tid; i < 34 * 64; i += 256) w_cp[i >> 6][i & 63] = cp_w[i];
  // feats + raw inputs (64*16 = 1024 items)
  #pragma unroll
  for (int it = 0; it < 4; ++it) {
    int i = it * 256 + tid; int p = i >> 4, f = i & 15;
    float n0 = nodes[(size_t)(p0 + p) * 2 + 0], n1 = nodes[(size_t)(p0 + p) * 2 + 1];
    float xb = n0 * coordB[f] + n1 * coordB[NFF + f];
    feats[p][2 + f] = sinf(xb);
    feats[p][2 + NFF + f] = cosf(xb);
    if (f == 0) {
      feats[p][0] = n0; feats[p][1] = n1;
      hin[p][0] = u[(size_t)(p0 + p) * 2 + 0];
      hin[p][1] = u[(size_t)(p0 + p) * 2 + 1];
    }
  }
  __syncthreads();
  // c-projection (64*64 = 4096 items)
  #pragma unroll
  for (int it = 0; it < 16; ++it) {
    int j = it * 256 + tid; int p = j >> 6, cc = j & 63;
    float acc = cp_b[cc];
    #pragma unroll
    for (int i = 0; i < 34; ++i) acc += feats[p][i] * w_cp[i][cc];
    hin[p][2 + cc] = acc;
  }
  __syncthreads();
  // h-projection (64*128 = 8192 items)
  #pragma unroll
  for (int it = 0; it < 32; ++it) {
    int j = it * 256 + tid; int p = j >> 7, d = j & 127;
    float acc = in_b[d];
    #pragma unroll
    for (int i = 0; i < 66; ++i) acc += hin[p][i] * w_in[i][d];
    h[(size_t)(p0 + p) * DD + d] = acc;
  }
}

__device__ __forceinline__ float basis_val(int t, float n0, float n1, const float* modes) {
  if (t >= 2 * KM) return (t == 2 * KM) ? 1.0f : 0.0f;
  int mi = t & (KM - 1);
  float th = n0 * modes[mi * 2 + 0] + n1 * modes[mi * 2 + 1];
  float s, c; __sincosf(th, &s, &c);
  return (t < KM) ? c : s;
}

// ---------------- basesT [b][t][x] single bf16 (slice B operand) ----------------
__global__ void k_basesT(const float* __restrict__ nodes, const float* __restrict__ modes,
                         bf16* __restrict__ bT) {
  int t = blockIdx.y, b = blockIdx.z;
  int x = blockIdx.x * 256 + threadIdx.x;
  float2 nd = *(const float2*)(nodes + ((size_t)b * NN + x) * 2);
  float v = basis_val(t, nd.x, nd.y, modes);
  bT[((size_t)b * TPAD + t) * NN + x] = __float2bfloat16(v);
}

// ---------------- basesR [b][x][t] single bf16 (deslice A operand) ----------------
__global__ void k_basesR(const float* __restrict__ nodes, const float* __restrict__ modes,
                         bf16* __restrict__ bR) {
  int p = blockIdx.x;          // b*N + x
  int t = threadIdx.x;         // 0..319
  float2 nd = *(const float2*)(nodes + (size_t)p * 2);
  float v = basis_val(t, nd.x, nd.y, modes);
  bR[(size_t)p * TPAD + t] = __float2bfloat16(v);
}

// ---------------- one-time: zero the Zt pad columns ----------------
__global__ void k_ztpad(bf16* __restrict__ Zt_hi, bf16* __restrict__ Zt_lo) {
  int i = blockIdx.x * 256 + threadIdx.x;
  int tot = BB * DD * (TPAD - MM);
  if (i >= tot) return;
  int bd = i / (TPAD - MM); int t = MM + i % (TPAD - MM);
  size_t idx = (size_t)bd * TPAD + t;
  Zt_hi[idx] = __float2bfloat16(0.f);
  Zt_lo[idx] = __float2bfloat16(0.f);
}

// ---------------- hTw init: [d][x] = h*w, hi/lo ----------------
__global__ void k_hTw(const float* __restrict__ h, const float* __restrict__ nw,
                      bf16* __restrict__ hw_hi, bf16* __restrict__ hw_lo) {
  int xt = blockIdx.x, b = blockIdx.y; int x0 = xt * 64;
  __shared__ float T[128][67];
  __shared__ float wls[64];
  int tid = threadIdx.x;
  if (tid < 64) wls[tid] = nw[(size_t)b * NN + x0 + tid];
  for (int it = 0; it < 32; ++it) {
    int eid = it * 256 + tid; int x = eid >> 7, d = eid & 127;
    T[d][x] = h[((size_t)b * NN + x0 + x) * DD + d];
  }
  __syncthreads();
  for (int it = 0; it < 32; ++it) {
    int eid = it * 256 + tid; int d = eid >> 6, xl = eid & 63;
    float v = T[d][xl] * wls[xl];
    bf16 hi, lo; split2(v, hi, lo);
    size_t idx = ((size_t)b * DD + d) * NN + x0 + xl;
    hw_hi[idx] = hi; hw_lo[idx] = lo;
  }
}

// ---------------- slice (MFMA, no LDS): partialT[b][ck][d][t] ----------------
__global__ void __launch_bounds__(256, 4)
k_slice(const bf16* __restrict__ bT, const bf16* __restrict__ hw_hi,
        const bf16* __restrict__ hw_lo, float* __restrict__ partialT) {
  int ck = blockIdx.x, tg = blockIdx.y, b = blockIdx.z;
  int kbase = ck * (NN / SKC);   // 512-chunk of x
  int tid = threadIdx.x, w = tid >> 6, lane = tid & 63, lr = lane & 15, lg = lane >> 4;
  const bf16* pAh = hw_hi + ((size_t)b * DD + w * 32 + lr) * NN + kbase + lg * 8;
  const bf16* pAl = hw_lo + ((size_t)b * DD + w * 32 + lr) * NN + kbase + lg * 8;
  const bf16* pB  = bT + ((size_t)b * TPAD + tg * 64 + lr) * NN + kbase + lg * 8;
  f32x4 acc[8];
  #pragma unroll
  for (int i = 0; i < 8; i++) acc[i] = (f32x4){0.f, 0.f, 0.f, 0.f};
  for (int kc = 0; kc < NN / SKC; kc += 64) {
    bf16x8 ah[2][2], al[2][2], bb[2][4];
    #pragma unroll
    for (int ks2 = 0; ks2 < 2; ++ks2) {
      int ko = kc + ks2 * 32;
      #pragma unroll
      for (int fi = 0; fi < 2; ++fi) {
        ah[ks2][fi] = *(const bf16x8*)(pAh + (size_t)fi * 16 * NN + ko);
        al[ks2][fi] = *(const bf16x8*)(pAl + (size_t)fi * 16 * NN + ko);
      }
      #pragma unroll
      for (int tc = 0; tc < 4; ++tc)
        bb[ks2][tc] = *(const bf16x8*)(pB + (size_t)tc * 16 * NN + ko);
    }
    #pragma unroll
    for (int ks2 = 0; ks2 < 2; ++ks2)
      #pragma unroll
      for (int fi = 0; fi < 2; ++fi)
        #pragma unroll
        for (int tc = 0; tc < 4; ++tc) {
          int ai = fi * 4 + tc;
          acc[ai] = __builtin_amdgcn_mfma_f32_16x16x32_bf16(ah[ks2][fi], bb[ks2][tc], acc[ai], 0, 0, 0);
          acc[ai] = __builtin_amdgcn_mfma_f32_16x16x32_bf16(al[ks2][fi], bb[ks2][tc], acc[ai], 0, 0, 0);
        }
  }
  float* pp = partialT + ((size_t)(b * SKC + ck) * DD) * TPAD;
  #pragma unroll
  for (int fi = 0; fi < 2; ++fi)
    #pragma unroll
    for (int tc = 0; tc < 4; ++tc)
      #pragma unroll
      for (int r = 0; r < 4; ++r) {
        int d = w * 32 + fi * 16 + lg * 4 + r;
        int t = tg * 64 + tc * 16 + lr;
        pp[(size_t)d * TPAD + t] = acc[fi * 4 + tc][r];
      }
}

// ---------------- reduce: Z[t][d] = sum_ck partialT[ck][d][t] ----------------
__global__ void k_reduce(const float* __restrict__ partialT, float* __restrict__ Z) {
  int idx = blockIdx.x * 256 + threadIdx.x;
  if (idx >= BB * DD * MM) return;
  int b = idx / (DD * MM); int rem = idx % (DD * MM); int d = rem / MM; int t = rem % MM;
  float s = 0.f;
  #pragma unroll
  for (int ck = 0; ck < SKC; ck++)
    s += partialT[((size_t)(b * SKC + ck) * DD + d) * TPAD + t];
  Z[((size_t)b * MM + t) * DD + d] = s;
}

// ---------------- qkv (fused LN1) ----------------
__global__ void k_qkv(const float* __restrict__ Z, const float* __restrict__ lnw,
                      const float* __restrict__ lnb, const float* __restrict__ W,
                      const float* __restrict__ bias, float* __restrict__ q,
                      float* __restrict__ k, float* __restrict__ v) {
  int row = blockIdx.x;            // b*M + t
  int b = row / MM, t = row % MM;
  int j = threadIdx.x;             // 0..383
  __shared__ float zr[128];
  __shared__ float red[4];
  if (j < 128) {
    float val = Z[(size_t)row * DD + j];
    zr[j] = val;
    float s = val, q2 = val * val;
    for (int off = 32; off; off >>= 1) { s += __shfl_xor(s, off); q2 += __shfl_xor(q2, off); }
    if ((j & 63) == 0) { red[(j >> 6) * 2] = s; red[(j >> 6) * 2 + 1] = q2; }
  }
  __syncthreads();
  float s = red[0] + red[2], q2 = red[1] + red[3];
  float mean = s / 128.f;
  float var = q2 / 128.f - mean * mean;
  float inv = rsqrtf(var + 1e-5f);
  if (j < 128) zr[j] = (zr[j] - mean) * inv * lnw[j] + lnb[j];
  __syncthreads();
  float acc = bias[j];
  for (int i = 0; i < 128; i++) acc += zr[i] * W[(size_t)i * 384 + j];
  int which = j >> 7;
  int jj = j & 127;
  int hh = jj >> 4, dh = jj & 15;
  float* dst = (which == 0) ? q : (which == 1) ? k : v;
  dst[((size_t)(b * HHD + hh) * MM + t) * DHH + dh] = acc;
}

// ---------------- attention (split-KV, 8 segs/row, shfl merge) ----------------
__global__ void __launch_bounds__(256, 4)
k_att(const float* __restrict__ q, const float* __restrict__ k,
      const float* __restrict__ v, float* __restrict__ obuf) {
  int bh = blockIdx.y; int b = bh / HHD, hh = bh % HHD;
  int rt = blockIdx.x;             // 0..8, rows rt*32 .. rt*32+31
  __shared__ float ks[MM * DHH];
  __shared__ float vs[MM * DHH];
  const float* kp = k + (size_t)bh * MM * DHH;
  const float* vp = v + (size_t)bh * MM * DHH;
  for (int i = threadIdx.x; i < MM * DHH; i += 256) { ks[i] = kp[i]; vs[i] = vp[i]; }
  __syncthreads();
  const float scale = 0.25f;
  int tid = threadIdx.x;
  int row = rt * 32 + (tid >> 3);
  int seg = tid & 7;
  float m = -1e30f, s = 0.f, o[16];
  #pragma unroll
  for (int j = 0; j < 16; j++) o[j] = 0.f;
  if (row < MM) {
    float qr[16];
    const float* qp = q + ((size_t)bh * MM + row) * DHH;
    #pragma unroll
    for (int j = 0; j < 16; j++) qr[j] = qp[j];
    int t0 = seg * 33;
    int t1 = t0 + 33; if (t1 > MM) t1 = MM;
    for (int t = t0; t < t1; t++) {
      float sc = 0.f;
      #pragma unroll
      for (int j = 0; j < 16; j++) sc += qr[j] * ks[t * 16 + j];
      sc *= scale;
      float mn = fmaxf(m, sc);
      float corr = __expf(m - mn);
      float e = __expf(sc - mn);
      s = s * corr + e;
      #pragma unroll
      for (int j = 0; j < 16; j++) o[j] = o[j] * corr + e * vs[t * 16 + j];
      m = mn;
    }
  }
  #pragma unroll
  for (int off2 = 1; off2 < 8; off2 <<= 1) {
    float m2 = __shfl_xor(m, off2);
    float s2 = __shfl_xor(s, off2);
    float mn = fmaxf(m, m2);
    float c1 = __expf(m - mn), c2 = __expf(m2 - mn);
    s = s * c1 + s2 * c2;
    #pragma unroll
    for (int j = 0; j < 16; j++) o[j] = o[j] * c1 + __shfl_xor(o[j], off2) * c2;
    m = mn;
  }
  if (seg == 0 && row < MM) {
    float invs = 1.f / s;
    float* op = obuf + ((size_t)(b * MM + row)) * DD + hh * DHH;
    #pragma unroll
    for (int j4 = 0; j4 < 4; ++j4) {
      float4 vv = make_float4(o[j4 * 4] * invs, o[j4 * 4 + 1] * invs,
                              o[j4 * 4 + 2] * invs, o[j4 * 4 + 3] * invs);
      *(float4*)(op + j4 * 4) = vv;
    }
  }
}

// ---------------- attn out proj -> Zt hi/lo directly (fused zt) ----------------
__global__ void k_ao(const float* __restrict__ obuf, const float* __restrict__ W,
                     const float* __restrict__ bias, const float* __restrict__ Z,
                     bf16* __restrict__ Zt_hi, bf16* __restrict__ Zt_lo) {
  int row = blockIdx.x; int d = threadIdx.x;
  int b = row / MM, t = row % MM;
  __shared__ float orow[128];
  orow[d] = obuf[(size_t)row * DD + d];
  __syncthreads();
  float acc = bias[d];
  for (int i = 0; i < 128; i++) acc += orow[i] * W[(size_t)i * DD + d];
  float nz = Z[(size_t)row * DD + d] + acc;
  bf16 hi, lo; split2(nz, hi, lo);
  size_t idx = ((size_t)b * DD + d) * TPAD + t;
  Zt_hi[idx] = hi; Zt_lo[idx] = lo;
}

// ------- deslice (MFMA, pure global like slice) + fused LN2 -> ln2h bf16 -------
__global__ void __launch_bounds__(256, 4)
k_deslice(const bf16* __restrict__ bR, const bf16* __restrict__ Zt_hi,
          const bf16* __restrict__ Zt_lo, const float* __restrict__ lw,
          const float* __restrict__ lb, float* __restrict__ h,
          bf16* __restrict__ ln2h) {
  int xt = blockIdx.x, b = blockIdx.y;
  int x0 = xt * 64;
  int tid = threadIdx.x, w = tid >> 6, lane = tid & 63, lr = lane & 15, lg = lane >> 4;
  const bf16* pA  = bR + ((size_t)b * NN + x0 + w * 16 + lr) * TPAD + lg * 8;
  const bf16* pBh = Zt_hi + ((size_t)b * DD + lr) * TPAD + lg * 8;
  const bf16* pBl = Zt_lo + ((size_t)b * DD + lr) * TPAD + lg * 8;
  f32x4 acc[8];
  #pragma unroll
  for (int i = 0; i < 8; i++) acc[i] = (f32x4){0.f, 0.f, 0.f, 0.f};
  for (int kc = 0; kc < TPAD; kc += 64) {
    #pragma unroll
    for (int ks2 = 0; ks2 < 2; ++ks2) {
      int ko = kc + ks2 * 32;
      bf16x8 a = *(const bf16x8*)(pA + ko);
      #pragma unroll
      for (int fg = 0; fg < 2; ++fg) {
        bf16x8 bh[4], bl[4];
        #pragma unroll
        for (int fj = 0; fj < 4; ++fj) {
          int fi = fg * 4 + fj;
          bh[fj] = *(const bf16x8*)(pBh + (size_t)fi * 16 * TPAD + ko);
          bl[fj] = *(const bf16x8*)(pBl + (size_t)fi * 16 * TPAD + ko);
        }
        #pragma unroll
        for (int fj = 0; fj < 4; ++fj) {
          int fi = fg * 4 + fj;
          acc[fi] = __builtin_amdgcn_mfma_f32_16x16x32_bf16(a, bh[fj], acc[fi], 0, 0, 0);
          acc[fi] = __builtin_amdgcn_mfma_f32_16x16x32_bf16(a, bl[fj], acc[fi], 0, 0, 0);
        }
      }
    }
  }
  float lwv[8], lbv[8];
  #pragma unroll
  for (int fi = 0; fi < 8; ++fi) { lwv[fi] = lw[fi * 16 + lr]; lbv[fi] = lb[fi * 16 + lr]; }
  float hv[8][4];
  float sm[4], sq[4];
  #pragma unroll
  for (int r = 0; r < 4; ++r) { sm[r] = 0.f; sq[r] = 0.f; }
  size_t rowbase = ((size_t)b * NN + x0 + w * 16 + lg * 4);
  #pragma unroll
  for (int fi = 0; fi < 8; ++fi)
    #pragma unroll
    for (int r = 0; r < 4; ++r) {
      float v = h[(rowbase + r) * DD + fi * 16 + lr] + acc[fi][r];
      hv[fi][r] = v; sm[r] += v; sq[r] += v * v;
    }
  #pragma unroll
  for (int r = 0; r < 4; ++r) {
    float s = sm[r], q = sq[r];
    s += __shfl_xor(s, 1); q += __shfl_xor(q, 1);
    s += __shfl_xor(s, 2); q += __shfl_xor(q, 2);
    s += __shfl_xor(s, 4); q += __shfl_xor(q, 4);
    s += __shfl_xor(s, 8); q += __shfl_xor(q, 8);
    float mean = s / 128.f;
    float var = q / 128.f - mean * mean;
    sm[r] = mean; sq[r] = rsqrtf(var + 1e-5f);
  }
  #pragma unroll
  for (int fi = 0; fi < 8; ++fi)
    #pragma unroll
    for (int r = 0; r < 4; ++r) {
      float v = hv[fi][r];
      h[(rowbase + r) * DD + fi * 16 + lr] = v;
      float ln = (v - sm[r]) * sq[r] * lwv[fi] + lbv[fi];
      ln2h[(rowbase + r) * DD + fi * 16 + lr] = __float2bfloat16(ln);
    }
}

// ------- ffnA (MFMA, 64-row blocks): mid = gelu(ln2h @ f1 + b1) bf16 -------
__global__ void __launch_bounds__(256, 2)
k_ffnA(const bf16* __restrict__ ln2h, const bf16* __restrict__ f1T_hi,
       const bf16* __restrict__ f1T_lo, const float* __restrict__ b1,
       bf16* __restrict__ mid) {
  int x0 = blockIdx.x * 64;
  int tid = threadIdx.x, w = tid >> 6, lane = tid & 63, lr = lane & 15, lg = lane >> 4;
  int f0 = w * 128;
  __shared__ short mid_s[16][DFFN + 8];
  f32x4 acc[4][8];
  #pragma unroll
  for (int rt = 0; rt < 4; ++rt)
    #pragma unroll
    for (int fi = 0; fi < 8; ++fi) acc[rt][fi] = (f32x4){0.f, 0.f, 0.f, 0.f};
  #pragma unroll
  for (int ks = 0; ks < 4; ++ks) {
    bf16x8 a[4];
    #pragma unroll
    for (int rt = 0; rt < 4; ++rt)
      a[rt] = *(const bf16x8*)(ln2h + ((size_t)x0 + rt * 16 + lr) * DD + ks * 32 + lg * 8);
    bf16x8 bh[8];
    #pragma unroll
    for (int fi = 0; fi < 8; ++fi)
      bh[fi] = *(const bf16x8*)(f1T_hi + (size_t)(f0 + fi * 16 + lr) * DD + ks * 32 + lg * 8);
    #pragma unroll
    for (int fi = 0; fi < 8; ++fi)
      #pragma unroll
      for (int rt = 0; rt < 4; ++rt)
        acc[rt][fi] = __builtin_amdgcn_mfma_f32_16x16x32_bf16(a[rt], bh[fi], acc[rt][fi], 0, 0, 0);
    bf16x8 bl[8];
    #pragma unroll
    for (int fi = 0; fi < 8; ++fi)
      bl[fi] = *(const bf16x8*)(f1T_lo + (size_t)(f0 + fi * 16 + lr) * DD + ks * 32 + lg * 8);
    #pragma unroll
    for (int fi = 0; fi < 8; ++fi)
      #pragma unroll
      for (int rt = 0; rt < 4; ++rt)
        acc[rt][fi] = __builtin_amdgcn_mfma_f32_16x16x32_bf16(a[rt], bl[fi], acc[rt][fi], 0, 0, 0);
  }
  #pragma unroll
  for (int rt = 0; rt < 4; ++rt) {
    __syncthreads();
    #pragma unroll
    for (int fi = 0; fi < 8; ++fi) {
      int col = f0 + fi * 16 + lr;
      float bb = b1[col];
      #pragma unroll
      for (int r = 0; r < 4; ++r) {
        float xx = acc[rt][fi][r] + bb;
        float gl = 0.5f * xx * (1.f + erff(xx * 0.70710678118654752f));
        mid_s[lg * 4 + r][col] = b2s(__float2bfloat16(gl));
      }
    }
    __syncthreads();
    #pragma unroll
    for (int it = 0; it < 4; ++it) {
      int eid = it * 256 + tid;
      int row = eid >> 6, c = eid & 63;
      uint4 vv = *(const uint4*)&mid_s[row][c * 8];
      *(uint4*)(mid + ((size_t)x0 + rt * 16 + row) * DFFN + c * 8) = vv;
    }
  }
}

// ------- ffnB (MFMA): wave owns 32 d-cols x all 64 rows; h += mid@f2 + b2 -------
__global__ void __launch_bounds__(256, 2)
k_ffnB(const bf16* __restrict__ mid, const bf16* __restrict__ f2T_hi,
       const bf16* __restrict__ f2T_lo, const float* __restrict__ b2,
       const float* __restrict__ nw, float* __restrict__ h,
       bf16* __restrict__ hw_hi, bf16* __restrict__ hw_lo) {
  int x0 = blockIdx.x * 64;
  int b = x0 / NN; int xb = x0 % NN;
  int tid = threadIdx.x, w = tid >> 6, lane = tid & 63, lr = lane & 15, lg = lane >> 4;
  int d0 = w * 32;
  __shared__ float T[128][67];
  __shared__ float wls[64];
  if (tid < 64) wls[tid] = nw[(size_t)b * NN + xb + tid];
  f32x4 acc[4][2];
  #pragma unroll
  for (int rt = 0; rt < 4; ++rt)
    #pragma unroll
    for (int dj = 0; dj < 2; ++dj) acc[rt][dj] = (f32x4){0.f, 0.f, 0.f, 0.f};
  #pragma unroll
  for (int ks = 0; ks < 16; ++ks) {
    bf16x8 a[4];
    #pragma unroll
    for (int rt = 0; rt < 4; ++rt)
      a[rt] = *(const bf16x8*)(mid + ((size_t)x0 + rt * 16 + lr) * DFFN + ks * 32 + lg * 8);
    bf16x8 bh[2], bl[2];
    #pragma unroll
    for (int dj = 0; dj < 2; ++dj) {
      size_t widx = (size_t)(d0 + dj * 16 + lr) * DFFN + ks * 32 + lg * 8;
      bh[dj] = *(const bf16x8*)(f2T_hi + widx);
      bl[dj] = *(const bf16x8*)(f2T_lo + widx);
    }
    #pragma unroll
    for (int dj = 0; dj < 2; ++dj)
      #pragma unroll
      for (int rt = 0; rt < 4; ++rt) {
        acc[rt][dj] = __builtin_amdgcn_mfma_f32_16x16x32_bf16(a[rt], bh[dj], acc[rt][dj], 0, 0, 0);
        acc[rt][dj] = __builtin_amdgcn_mfma_f32_16x16x32_bf16(a[rt], bl[dj], acc[rt][dj], 0, 0, 0);
      }
  }
  #pragma unroll
  for (int dj = 0; dj < 2; ++dj) {
    int d = d0 + dj * 16 + lr;
    float bb = b2[d];
    #pragma unroll
    for (int rt = 0; rt < 4; ++rt)
      #pragma unroll
      for (int r = 0; r < 4; ++r) {
        int rowl = rt * 16 + lg * 4 + r;
        float v = h[((size_t)x0 + rowl) * DD + d] + acc[rt][dj][r] + bb;
        h[((size_t)x0 + rowl) * DD + d] = v;
        T[d][rowl] = v;
      }
  }
  __syncthreads();
  for (int it = 0; it < 32; ++it) {
    int eid = it * 256 + tid; int d = eid >> 6, xl = eid & 63;
    float v = T[d][xl] * wls[xl];
    bf16 hi, lo; split2(v, hi, lo);
    size_t idx = ((size_t)b * DD + d) * NN + xb + xl;
    hw_hi[idx] = hi; hw_lo[idx] = lo;
  }
}

// ---------------- final LN + out proj (f32 out) ----------------
__global__ void k_out(const float* __restrict__ h, const float* __restrict__ lw,
                      const float* __restrict__ lb, const float* __restrict__ ow,
                      const float* __restrict__ ob, float* __restrict__ out) {
  int row = blockIdx.x; int tid = threadIdx.x;
  float v = h[(size_t)row * DD + tid];
  float s = v, q = v * v;
  for (int off = 32; off; off >>= 1) { s += __shfl_xor(s, off); q += __shfl_xor(q, off); }
  __shared__ float sh[4];
  __shared__ float sp[4];
  int wv = tid >> 6;
  if ((tid & 63) == 0) { sh[wv] = s; sh[2 + wv] = q; }
  __syncthreads();
  s = sh[0] + sh[1]; q = sh[2] + sh[3];
  float mean = s / 128.f, var = q / 128.f - mean * mean;
  float inv = rsqrtf(var + 1e-5f);
  float ln = (v - mean) * inv * lw[tid] + lb[tid];
  float p0 = ln * ow[tid * 2 + 0], p1 = ln * ow[tid * 2 + 1];
  for (int off = 32; off; off >>= 1) { p0 += __shfl_xor(p0, off); p1 += __shfl_xor(p1, off); }
  if ((tid & 63) == 0) { sp[wv] = p0; sp[2 + wv] = p1; }
  __syncthreads();
  if (tid == 0) out[(size_t)row * 2 + 0] = sp[0] + sp[1] + ob[0];
  if (tid == 1) out[(size_t)row * 2 + 1] = sp[2] + sp[3] + ob[1];
}

extern "C" void kernel_launch(void* const* d_in, const int* in_sizes, int n_in,
                              void* d_out, int out_size, void* d_ws, size_t ws_size,
                              hipStream_t stream) {
  const float* u      = (const float*)d_in[0];
  const float* nodes  = (const float*)d_in[1];
  const float* nw     = (const float*)d_in[2];
  const float* modes  = (const float*)d_in[3];
  const float* coordB = (const float*)d_in[4];
  const float* cp_w   = (const float*)d_in[5];
  const float* cp_b   = (const float*)d_in[6];
  const float* in_w   = (const float*)d_in[7];
  const float* in_b   = (const float*)d_in[8];
  const float* ln1_w  = (const float*)d_in[9];
  const float* ln1_b  = (const float*)d_in[10];
  const float* qkv_w  = (const float*)d_in[11];
  const float* qkv_b  = (const float*)d_in[12];
  const float* ao_w   = (const float*)d_in[13];
  const float* ao_b   = (const float*)d_in[14];
  const float* f1_w   = (const float*)d_in[15];
  const float* f1_b   = (const float*)d_in[16];
  const float* f2_w   = (const float*)d_in[17];
  const float* f2_b   = (const float*)d_in[18];
  const float* ln2_w  = (const float*)d_in[19];
  const float* ln2_b  = (const float*)d_in[20];
  const float* lnf_w  = (const float*)d_in[21];
  const float* lnf_b  = (const float*)d_in[22];
  const float* out_w  = (const float*)d_in[23];
  const float* out_b  = (const float*)d_in[24];

  char* ws = (char*)d_ws;
  size_t off = 0;
  bf16* bT    = (bf16*)(ws + off); off += (size_t)BB * TPAD * NN * 2;   // 41.9 MB
  bf16* bR    = (bf16*)(ws + off); off += (size_t)BB * NN * TPAD * 2;   // 41.9 MB
  float* h    = (float*)(ws + off); off += (size_t)BB * NN * DD * 4;    // 33.6 MB
  bf16* hw_hi = (bf16*)(ws + off); off += (size_t)BB * DD * NN * 2;     // 16.8 MB
  bf16* hw_lo = (bf16*)(ws + off); off += (size_t)BB * DD * NN * 2;     // 16.8 MB
  bf16* ln2h  = (bf16*)(ws + off); off += (size_t)BB * NN * DD * 2;     // 16.8 MB
  char* regMid = ws + off; off += (size_t)BB * NN * DFFN * 2;           // 67.1 MB
  float* partialT = (float*)regMid;                       // live: slice -> reduce
  bf16*  mid      = (bf16*)regMid;                        // live: ffnA -> ffnB
  float* qb  = (float*)(regMid + 40 * 1024 * 1024);       // live: qkv -> att
  float* kb  = qb  + (size_t)BB * MM * DD;
  float* vb  = kb  + (size_t)BB * MM * DD;
  float* ob2 = vb  + (size_t)BB * MM * DD;                // live: att -> ao
  float* Z    = (float*)(ws + off); off += (size_t)BB * MM * DD * 4;
  bf16* Zt_hi = (bf16*)(ws + off); off += (size_t)BB * DD * TPAD * 2;
  bf16* Zt_lo = (bf16*)(ws + off); off += (size_t)BB * DD * TPAD * 2;
  bf16* f1T_hi = (bf16*)(ws + off); off += (size_t)LL * DFFN * DD * 2;
  bf16* f1T_lo = (bf16*)(ws + off); off += (size_t)LL * DFFN * DD * 2;
  bf16* f2T_hi = (bf16*)(ws + off); off += (size_t)LL * DD * DFFN * 2;
  bf16* f2T_lo = (bf16*)(ws + off); off += (size_t)LL * DD * DFFN * 2;
  // total ~239.2 MB

  k_prepW<<<(2 * LL * DFFN * DD + 255) / 256, 256, 0, stream>>>(f1_w, f2_w, f1T_hi, f1T_lo, f2T_hi, f2T_lo);
  k_embed<<<BB * NN / 64, 256, 0, stream>>>(u, nodes, coordB, cp_w, cp_b, in_w, in_b, h);
  k_basesT<<<dim3(NN / 256, TPAD, BB), 256, 0, stream>>>(nodes, modes, bT);
  k_basesR<<<BB * NN, TPAD, 0, stream>>>(nodes, modes, bR);
  k_hTw<<<dim3(NN / 64, BB), 256, 0, stream>>>(h, nw, hw_hi, hw_lo);
  k_ztpad<<<(BB * DD * (TPAD - MM) + 255) / 256, 256, 0, stream>>>(Zt_hi, Zt_lo);

  for (int l = 0; l < LL; l++) {
    k_slice<<<dim3(SKC, TPAD / 64, BB), 256, 0, stream>>>(bT, hw_hi, hw_lo, partialT);
    k_reduce<<<(BB * DD * MM + 255) / 256, 256, 0, stream>>>(partialT, Z);
    k_qkv<<<BB * MM, 384, 0, stream>>>(Z, ln1_w + l * DD, ln1_b + l * DD,
                                       qkv_w + (size_t)l * DD * 3 * DD, qkv_b + l * 3 * DD, qb, kb, vb);
    k_att<<<dim3(9, BB * HHD), 256, 0, stream>>>(qb, kb, vb, ob2);
    k_ao<<<BB * MM, 128, 0, stream>>>(ob2, ao_w + (size_t)l * DD * DD, ao_b + l * DD, Z, Zt_hi, Zt_lo);
    k_deslice<<<dim3(NN / 64, BB), 256, 0, stream>>>(bR, Zt_hi, Zt_lo,
                                                     ln2_w + l * DD, ln2_b + l * DD, h, ln2h);
    k_ffnA<<<BB * NN / 64, 256, 0, stream>>>(ln2h, f1T_hi + (size_t)l * DFFN * DD,
                                             f1T_lo + (size_t)l * DFFN * DD, f1_b + l * DFFN, mid);
    k_ffnB<<<BB * NN / 64, 256, 0, stream>>>(mid, f2T_hi + (size_t)l * DD * DFFN,
                                             f2T_lo + (size_t)l * DD * DFFN, f2_b + l * DD,
                                             nw, h, hw_hi, hw_lo);
  }
  k_out<<<BB * NN, 128, 0, stream>>>(h, lnf_w, lnf_b, out_w, out_b, (float*)d_out);
}

// Round 15
// 1785.359 us; speedup vs baseline: 1.2300x; 1.1287x over previous
//
#include <hip/hip_runtime.h>
#include <hip/hip_bf16.h>
#include <math.h>

#define BB 4
#define NN 16384
#define KM 128
#define DD 128
#define HHD 8
#define LL 6
#define DFFN 512
#define NFF 16
#define DCC 64
#define MM 257
#define DHH 16
#define SKC 32      // split-K chunks for slice
#define TPAD 320    // t-dim padded

typedef __hip_bfloat16 bf16;
using bf16x8 = __attribute__((ext_vector_type(8))) short;
using f32x4  = __attribute__((ext_vector_type(4))) float;

__device__ __forceinline__ void split2(float v, bf16& hi, bf16& lo) {
  hi = __float2bfloat16(v);
  lo = __float2bfloat16(v - __bfloat162float(hi));
}
__device__ __forceinline__ short b2s(bf16 x) {
  union { bf16 b; short s; } u; u.b = x; return u.s;
}

// ---------------- prep: bf16 hi/lo transposed FFN weights ----------------
__global__ void k_prepW(const float* __restrict__ f1_w, const float* __restrict__ f2_w,
                        bf16* __restrict__ f1T_hi, bf16* __restrict__ f1T_lo,
                        bf16* __restrict__ f2T_hi, bf16* __restrict__ f2T_lo) {
  size_t i = (size_t)blockIdx.x * 256 + threadIdx.x;
  size_t n = (size_t)LL * DFFN * DD;
  if (i < n) {
    int l = i / (DFFN * DD); int rem = i % (DFFN * DD); int f = rem / DD; int d = rem % DD;
    bf16 hi, lo; split2(f1_w[(size_t)l * DD * DFFN + (size_t)d * DFFN + f], hi, lo);
    f1T_hi[i] = hi; f1T_lo[i] = lo;
  } else if (i < 2 * n) {
    size_t j = i - n;
    int l = j / (DD * DFFN); int rem = j % (DD * DFFN); int d = rem / DFFN; int f = rem % DFFN;
    bf16 hi, lo; split2(f2_w[(size_t)l * DFFN * DD + (size_t)f * DD + d], hi, lo);
    f2T_hi[j] = hi; f2T_lo[j] = lo;
  }
}

// ------- embed v4: 64 pts/block, weights+feats+hin in LDS, 3 barriers -------
__global__ void __launch_bounds__(256)
k_embed(const float* __restrict__ u, const float* __restrict__ nodes,
        const float* __restrict__ coordB,
        const float* __restrict__ cp_w, const float* __restrict__ cp_b,
        const float* __restrict__ in_w, const float* __restrict__ in_b,
        float* __restrict__ h) {
  int p0 = blockIdx.x * 64;
  int tid = threadIdx.x;
  __shared__ float w_in[66][128];   // 33.8 KB
  __shared__ float w_cp[34][64];    // 8.7 KB
  __shared__ float feats[64][34];   // 8.7 KB
  __shared__ float hin[64][68];     // 17.4 KB
  for (int i = tid; i < 66 * 128; i += 256) w_in[i >> 7][i & 127] = in_w[i];
  for (int i = tid; i < 34 * 64; i += 256) w_cp[i >> 6][i & 63] = cp_w[i];
  #pragma unroll
  for (int it = 0; it < 4; ++it) {
    int i = it * 256 + tid; int p = i >> 4, f = i & 15;
    float n0 = nodes[(size_t)(p0 + p) * 2 + 0], n1 = nodes[(size_t)(p0 + p) * 2 + 1];
    float xb = n0 * coordB[f] + n1 * coordB[NFF + f];
    feats[p][2 + f] = sinf(xb);
    feats[p][2 + NFF + f] = cosf(xb);
    if (f == 0) {
      feats[p][0] = n0; feats[p][1] = n1;
      hin[p][0] = u[(size_t)(p0 + p) * 2 + 0];
      hin[p][1] = u[(size_t)(p0 + p) * 2 + 1];
    }
  }
  __syncthreads();
  #pragma unroll
  for (int it = 0; it < 16; ++it) {
    int j = it * 256 + tid; int p = j >> 6, cc = j & 63;
    float acc = cp_b[cc];
    #pragma unroll
    for (int i = 0; i < 34; ++i) acc += feats[p][i] * w_cp[i][cc];
    hin[p][2 + cc] = acc;
  }
  __syncthreads();
  #pragma unroll
  for (int it = 0; it < 32; ++it) {
    int j = it * 256 + tid; int p = j >> 7, d = j & 127;
    float acc = in_b[d];
    #pragma unroll
    for (int i = 0; i < 66; ++i) acc += hin[p][i] * w_in[i][d];
    h[(size_t)(p0 + p) * DD + d] = acc;
  }
}

__device__ __forceinline__ float basis_val(int t, float n0, float n1, const float* modes) {
  if (t >= 2 * KM) return (t == 2 * KM) ? 1.0f : 0.0f;
  int mi = t & (KM - 1);
  float th = n0 * modes[mi * 2 + 0] + n1 * modes[mi * 2 + 1];
  float s, c; __sincosf(th, &s, &c);
  return (t < KM) ? c : s;
}

// ---------------- basesT [b][t][x] single bf16 (slice B operand) ----------------
__global__ void k_basesT(const float* __restrict__ nodes, const float* __restrict__ modes,
                         bf16* __restrict__ bT) {
  int t = blockIdx.y, b = blockIdx.z;
  int x = blockIdx.x * 256 + threadIdx.x;
  float2 nd = *(const float2*)(nodes + ((size_t)b * NN + x) * 2);
  float v = basis_val(t, nd.x, nd.y, modes);
  bT[((size_t)b * TPAD + t) * NN + x] = __float2bfloat16(v);
}

// ---------------- basesR [b][x][t] single bf16 (deslice A operand) ----------------
__global__ void k_basesR(const float* __restrict__ nodes, const float* __restrict__ modes,
                         bf16* __restrict__ bR) {
  int p = blockIdx.x;          // b*N + x
  int t = threadIdx.x;         // 0..319
  float2 nd = *(const float2*)(nodes + (size_t)p * 2);
  float v = basis_val(t, nd.x, nd.y, modes);
  bR[(size_t)p * TPAD + t] = __float2bfloat16(v);
}

// ---------------- one-time: zero the Zt pad columns ----------------
__global__ void k_ztpad(bf16* __restrict__ Zt) {
  int i = blockIdx.x * 256 + threadIdx.x;
  int tot = BB * DD * (TPAD - MM);
  if (i >= tot) return;
  int bd = i / (TPAD - MM); int t = MM + i % (TPAD - MM);
  Zt[(size_t)bd * TPAD + t] = __float2bfloat16(0.f);
}

// ---------------- hTw init: [d][x] = h*w, hi/lo ----------------
__global__ void k_hTw(const float* __restrict__ h, const float* __restrict__ nw,
                      bf16* __restrict__ hw_hi, bf16* __restrict__ hw_lo) {
  int xt = blockIdx.x, b = blockIdx.y; int x0 = xt * 64;
  __shared__ float T[128][67];
  __shared__ float wls[64];
  int tid = threadIdx.x;
  if (tid < 64) wls[tid] = nw[(size_t)b * NN + x0 + tid];
  for (int it = 0; it < 32; ++it) {
    int eid = it * 256 + tid; int x = eid >> 7, d = eid & 127;
    T[d][x] = h[((size_t)b * NN + x0 + x) * DD + d];
  }
  __syncthreads();
  for (int it = 0; it < 32; ++it) {
    int eid = it * 256 + tid; int d = eid >> 6, xl = eid & 63;
    float v = T[d][xl] * wls[xl];
    bf16 hi, lo; split2(v, hi, lo);
    size_t idx = ((size_t)b * DD + d) * NN + x0 + xl;
    hw_hi[idx] = hi; hw_lo[idx] = lo;
  }
}

// ---------------- slice (MFMA, no LDS): partialT[b][ck][d][t] ----------------
__global__ void __launch_bounds__(256, 4)
k_slice(const bf16* __restrict__ bT, const bf16* __restrict__ hw_hi,
        const bf16* __restrict__ hw_lo, float* __restrict__ partialT) {
  int ck = blockIdx.x, tg = blockIdx.y, b = blockIdx.z;
  int kbase = ck * (NN / SKC);   // 512-chunk of x
  int tid = threadIdx.x, w = tid >> 6, lane = tid & 63, lr = lane & 15, lg = lane >> 4;
  const bf16* pAh = hw_hi + ((size_t)b * DD + w * 32 + lr) * NN + kbase + lg * 8;
  const bf16* pAl = hw_lo + ((size_t)b * DD + w * 32 + lr) * NN + kbase + lg * 8;
  const bf16* pB  = bT + ((size_t)b * TPAD + tg * 64 + lr) * NN + kbase + lg * 8;
  f32x4 acc[8];
  #pragma unroll
  for (int i = 0; i < 8; i++) acc[i] = (f32x4){0.f, 0.f, 0.f, 0.f};
  for (int kc = 0; kc < NN / SKC; kc += 64) {
    bf16x8 ah[2][2], al[2][2], bb[2][4];
    #pragma unroll
    for (int ks2 = 0; ks2 < 2; ++ks2) {
      int ko = kc + ks2 * 32;
      #pragma unroll
      for (int fi = 0; fi < 2; ++fi) {
        ah[ks2][fi] = *(const bf16x8*)(pAh + (size_t)fi * 16 * NN + ko);
        al[ks2][fi] = *(const bf16x8*)(pAl + (size_t)fi * 16 * NN + ko);
      }
      #pragma unroll
      for (int tc = 0; tc < 4; ++tc)
        bb[ks2][tc] = *(const bf16x8*)(pB + (size_t)tc * 16 * NN + ko);
    }
    #pragma unroll
    for (int ks2 = 0; ks2 < 2; ++ks2)
      #pragma unroll
      for (int fi = 0; fi < 2; ++fi)
        #pragma unroll
        for (int tc = 0; tc < 4; ++tc) {
          int ai = fi * 4 + tc;
          acc[ai] = __builtin_amdgcn_mfma_f32_16x16x32_bf16(ah[ks2][fi], bb[ks2][tc], acc[ai], 0, 0, 0);
          acc[ai] = __builtin_amdgcn_mfma_f32_16x16x32_bf16(al[ks2][fi], bb[ks2][tc], acc[ai], 0, 0, 0);
        }
  }
  float* pp = partialT + ((size_t)(b * SKC + ck) * DD) * TPAD;
  #pragma unroll
  for (int fi = 0; fi < 2; ++fi)
    #pragma unroll
    for (int tc = 0; tc < 4; ++tc)
      #pragma unroll
      for (int r = 0; r < 4; ++r) {
        int d = w * 32 + fi * 16 + lg * 4 + r;
        int t = tg * 64 + tc * 16 + lr;
        pp[(size_t)d * TPAD + t] = acc[fi * 4 + tc][r];
      }
}

// ---------------- reduce: Z[t][d] = sum_ck partialT[ck][d][t] ----------------
__global__ void k_reduce(const float* __restrict__ partialT, float* __restrict__ Z) {
  int idx = blockIdx.x * 256 + threadIdx.x;
  if (idx >= BB * DD * MM) return;
  int b = idx / (DD * MM); int rem = idx % (DD * MM); int d = rem / MM; int t = rem % MM;
  float s = 0.f;
  #pragma unroll
  for (int ck = 0; ck < SKC; ck++)
    s += partialT[((size_t)(b * SKC + ck) * DD + d) * TPAD + t];
  Z[((size_t)b * MM + t) * DD + d] = s;
}

// ---------------- qkv (fused LN1) ----------------
__global__ void k_qkv(const float* __restrict__ Z, const float* __restrict__ lnw,
                      const float* __restrict__ lnb, const float* __restrict__ W,
                      const float* __restrict__ bias, float* __restrict__ q,
                      float* __restrict__ k, float* __restrict__ v) {
  int row = blockIdx.x;            // b*M + t
  int b = row / MM, t = row % MM;
  int j = threadIdx.x;             // 0..383
  __shared__ float zr[128];
  __shared__ float red[4];
  if (j < 128) {
    float val = Z[(size_t)row * DD + j];
    zr[j] = val;
    float s = val, q2 = val * val;
    for (int off = 32; off; off >>= 1) { s += __shfl_xor(s, off); q2 += __shfl_xor(q2, off); }
    if ((j & 63) == 0) { red[(j >> 6) * 2] = s; red[(j >> 6) * 2 + 1] = q2; }
  }
  __syncthreads();
  float s = red[0] + red[2], q2 = red[1] + red[3];
  float mean = s / 128.f;
  float var = q2 / 128.f - mean * mean;
  float inv = rsqrtf(var + 1e-5f);
  if (j < 128) zr[j] = (zr[j] - mean) * inv * lnw[j] + lnb[j];
  __syncthreads();
  float acc = bias[j];
  for (int i = 0; i < 128; i++) acc += zr[i] * W[(size_t)i * 384 + j];
  int which = j >> 7;
  int jj = j & 127;
  int hh = jj >> 4, dh = jj & 15;
  float* dst = (which == 0) ? q : (which == 1) ? k : v;
  dst[((size_t)(b * HHD + hh) * MM + t) * DHH + dh] = acc;
}

// ---------------- attention (split-KV, 8 segs/row, shfl merge) ----------------
__global__ void __launch_bounds__(256, 4)
k_att(const float* __restrict__ q, const float* __restrict__ k,
      const float* __restrict__ v, float* __restrict__ obuf) {
  int bh = blockIdx.y; int b = bh / HHD, hh = bh % HHD;
  int rt = blockIdx.x;             // 0..8, rows rt*32 .. rt*32+31
  __shared__ float ks[MM * DHH];
  __shared__ float vs[MM * DHH];
  const float* kp = k + (size_t)bh * MM * DHH;
  const float* vp = v + (size_t)bh * MM * DHH;
  for (int i = threadIdx.x; i < MM * DHH; i += 256) { ks[i] = kp[i]; vs[i] = vp[i]; }
  __syncthreads();
  const float scale = 0.25f;
  int tid = threadIdx.x;
  int row = rt * 32 + (tid >> 3);
  int seg = tid & 7;
  float m = -1e30f, s = 0.f, o[16];
  #pragma unroll
  for (int j = 0; j < 16; j++) o[j] = 0.f;
  if (row < MM) {
    float qr[16];
    const float* qp = q + ((size_t)bh * MM + row) * DHH;
    #pragma unroll
    for (int j = 0; j < 16; j++) qr[j] = qp[j];
    int t0 = seg * 33;
    int t1 = t0 + 33; if (t1 > MM) t1 = MM;
    for (int t = t0; t < t1; t++) {
      float sc = 0.f;
      #pragma unroll
      for (int j = 0; j < 16; j++) sc += qr[j] * ks[t * 16 + j];
      sc *= scale;
      float mn = fmaxf(m, sc);
      float corr = __expf(m - mn);
      float e = __expf(sc - mn);
      s = s * corr + e;
      #pragma unroll
      for (int j = 0; j < 16; j++) o[j] = o[j] * corr + e * vs[t * 16 + j];
      m = mn;
    }
  }
  #pragma unroll
  for (int off2 = 1; off2 < 8; off2 <<= 1) {
    float m2 = __shfl_xor(m, off2);
    float s2 = __shfl_xor(s, off2);
    float mn = fmaxf(m, m2);
    float c1 = __expf(m - mn), c2 = __expf(m2 - mn);
    s = s * c1 + s2 * c2;
    #pragma unroll
    for (int j = 0; j < 16; j++) o[j] = o[j] * c1 + __shfl_xor(o[j], off2) * c2;
    m = mn;
  }
  if (seg == 0 && row < MM) {
    float invs = 1.f / s;
    float* op = obuf + ((size_t)(b * MM + row)) * DD + hh * DHH;
    #pragma unroll
    for (int j4 = 0; j4 < 4; ++j4) {
      float4 vv = make_float4(o[j4 * 4] * invs, o[j4 * 4 + 1] * invs,
                              o[j4 * 4 + 2] * invs, o[j4 * 4 + 3] * invs);
      *(float4*)(op + j4 * 4) = vv;
    }
  }
}

// ---------------- attn out proj -> Zt single bf16 (fused zt) ----------------
__global__ void k_ao(const float* __restrict__ obuf, const float* __restrict__ W,
                     const float* __restrict__ bias, const float* __restrict__ Z,
                     bf16* __restrict__ Zt) {
  int row = blockIdx.x; int d = threadIdx.x;
  int b = row / MM, t = row % MM;
  __shared__ float orow[128];
  orow[d] = obuf[(size_t)row * DD + d];
  __syncthreads();
  float acc = bias[d];
  for (int i = 0; i < 128; i++) acc += orow[i] * W[(size_t)i * DD + d];
  float nz = Z[(size_t)row * DD + d] + acc;
  Zt[((size_t)b * DD + d) * TPAD + t] = __float2bfloat16(nz);
}

// ------- deslice (MFMA, pure global, single-bf16 Zt) + fused LN2 -> ln2h -------
__global__ void __launch_bounds__(256, 4)
k_deslice(const bf16* __restrict__ bR, const bf16* __restrict__ Zt,
          const float* __restrict__ lw, const float* __restrict__ lb,
          float* __restrict__ h, bf16* __restrict__ ln2h) {
  int xt = blockIdx.x, b = blockIdx.y;
  int x0 = xt * 64;
  int tid = threadIdx.x, w = tid >> 6, lane = tid & 63, lr = lane & 15, lg = lane >> 4;
  const bf16* pA = bR + ((size_t)b * NN + x0 + w * 16 + lr) * TPAD + lg * 8;
  const bf16* pB = Zt + ((size_t)b * DD + lr) * TPAD + lg * 8;
  f32x4 acc[8];
  #pragma unroll
  for (int i = 0; i < 8; i++) acc[i] = (f32x4){0.f, 0.f, 0.f, 0.f};
  for (int kc = 0; kc < TPAD; kc += 64) {
    #pragma unroll
    for (int ks2 = 0; ks2 < 2; ++ks2) {
      int ko = kc + ks2 * 32;
      bf16x8 a = *(const bf16x8*)(pA + ko);
      bf16x8 bb[8];
      #pragma unroll
      for (int fi = 0; fi < 8; ++fi)
        bb[fi] = *(const bf16x8*)(pB + (size_t)fi * 16 * TPAD + ko);
      #pragma unroll
      for (int fi = 0; fi < 8; ++fi)
        acc[fi] = __builtin_amdgcn_mfma_f32_16x16x32_bf16(a, bb[fi], acc[fi], 0, 0, 0);
    }
  }
  float lwv[8], lbv[8];
  #pragma unroll
  for (int fi = 0; fi < 8; ++fi) { lwv[fi] = lw[fi * 16 + lr]; lbv[fi] = lb[fi * 16 + lr]; }
  float hv[8][4];
  float sm[4], sq[4];
  #pragma unroll
  for (int r = 0; r < 4; ++r) { sm[r] = 0.f; sq[r] = 0.f; }
  size_t rowbase = ((size_t)b * NN + x0 + w * 16 + lg * 4);
  #pragma unroll
  for (int fi = 0; fi < 8; ++fi)
    #pragma unroll
    for (int r = 0; r < 4; ++r) {
      float v = h[(rowbase + r) * DD + fi * 16 + lr] + acc[fi][r];
      hv[fi][r] = v; sm[r] += v; sq[r] += v * v;
    }
  #pragma unroll
  for (int r = 0; r < 4; ++r) {
    float s = sm[r], q = sq[r];
    s += __shfl_xor(s, 1); q += __shfl_xor(q, 1);
    s += __shfl_xor(s, 2); q += __shfl_xor(q, 2);
    s += __shfl_xor(s, 4); q += __shfl_xor(q, 4);
    s += __shfl_xor(s, 8); q += __shfl_xor(q, 8);
    float mean = s / 128.f;
    float var = q / 128.f - mean * mean;
    sm[r] = mean; sq[r] = rsqrtf(var + 1e-5f);
  }
  #pragma unroll
  for (int fi = 0; fi < 8; ++fi)
    #pragma unroll
    for (int r = 0; r < 4; ++r) {
      float v = hv[fi][r];
      h[(rowbase + r) * DD + fi * 16 + lr] = v;
      float ln = (v - sm[r]) * sq[r] * lwv[fi] + lbv[fi];
      ln2h[(rowbase + r) * DD + fi * 16 + lr] = __float2bfloat16(ln);
    }
}

// ------- ffnA (MFMA, 64-row blocks): mid = gelu(ln2h @ f1 + b1) bf16 -------
__global__ void __launch_bounds__(256, 2)
k_ffnA(const bf16* __restrict__ ln2h, const bf16* __restrict__ f1T_hi,
       const bf16* __restrict__ f1T_lo, const float* __restrict__ b1,
       bf16* __restrict__ mid) {
  int x0 = blockIdx.x * 64;
  int tid = threadIdx.x, w = tid >> 6, lane = tid & 63, lr = lane & 15, lg = lane >> 4;
  int f0 = w * 128;
  __shared__ short mid_s[16][DFFN + 8];
  f32x4 acc[4][8];
  #pragma unroll
  for (int rt = 0; rt < 4; ++rt)
    #pragma unroll
    for (int fi = 0; fi < 8; ++fi) acc[rt][fi] = (f32x4){0.f, 0.f, 0.f, 0.f};
  #pragma unroll
  for (int ks = 0; ks < 4; ++ks) {
    bf16x8 a[4];
    #pragma unroll
    for (int rt = 0; rt < 4; ++rt)
      a[rt] = *(const bf16x8*)(ln2h + ((size_t)x0 + rt * 16 + lr) * DD + ks * 32 + lg * 8);
    bf16x8 bh[8];
    #pragma unroll
    for (int fi = 0; fi < 8; ++fi)
      bh[fi] = *(const bf16x8*)(f1T_hi + (size_t)(f0 + fi * 16 + lr) * DD + ks * 32 + lg * 8);
    #pragma unroll
    for (int fi = 0; fi < 8; ++fi)
      #pragma unroll
      for (int rt = 0; rt < 4; ++rt)
        acc[rt][fi] = __builtin_amdgcn_mfma_f32_16x16x32_bf16(a[rt], bh[fi], acc[rt][fi], 0, 0, 0);
    bf16x8 bl[8];
    #pragma unroll
    for (int fi = 0; fi < 8; ++fi)
      bl[fi] = *(const bf16x8*)(f1T_lo + (size_t)(f0 + fi * 16 + lr) * DD + ks * 32 + lg * 8);
    #pragma unroll
    for (int fi = 0; fi < 8; ++fi)
      #pragma unroll
      for (int rt = 0; rt < 4; ++rt)
        acc[rt][fi] = __builtin_amdgcn_mfma_f32_16x16x32_bf16(a[rt], bl[fi], acc[rt][fi], 0, 0, 0);
  }
  #pragma unroll
  for (int rt = 0; rt < 4; ++rt) {
    __syncthreads();
    #pragma unroll
    for (int fi = 0; fi < 8; ++fi) {
      int col = f0 + fi * 16 + lr;
      float bb = b1[col];
      #pragma unroll
      for (int r = 0; r < 4; ++r) {
        float xx = acc[rt][fi][r] + bb;
        float gl = 0.5f * xx * (1.f + erff(xx * 0.70710678118654752f));
        mid_s[lg * 4 + r][col] = b2s(__float2bfloat16(gl));
      }
    }
    __syncthreads();
    #pragma unroll
    for (int it = 0; it < 4; ++it) {
      int eid = it * 256 + tid;
      int row = eid >> 6, c = eid & 63;
      uint4 vv = *(const uint4*)&mid_s[row][c * 8];
      *(uint4*)(mid + ((size_t)x0 + rt * 16 + row) * DFFN + c * 8) = vv;
    }
  }
}

// ------- ffnB (MFMA): wave owns 32 d-cols x all 64 rows; h += mid@f2 + b2 -------
__global__ void __launch_bounds__(256, 2)
k_ffnB(const bf16* __restrict__ mid, const bf16* __restrict__ f2T_hi,
       const bf16* __restrict__ f2T_lo, const float* __restrict__ b2,
       const float* __restrict__ nw, float* __restrict__ h,
       bf16* __restrict__ hw_hi, bf16* __restrict__ hw_lo) {
  int x0 = blockIdx.x * 64;
  int b = x0 / NN; int xb = x0 % NN;
  int tid = threadIdx.x, w = tid >> 6, lane = tid & 63, lr = lane & 15, lg = lane >> 4;
  int d0 = w * 32;
  __shared__ float T[128][67];
  __shared__ float wls[64];
  if (tid < 64) wls[tid] = nw[(size_t)b * NN + xb + tid];
  f32x4 acc[4][2];
  #pragma unroll
  for (int rt = 0; rt < 4; ++rt)
    #pragma unroll
    for (int dj = 0; dj < 2; ++dj) acc[rt][dj] = (f32x4){0.f, 0.f, 0.f, 0.f};
  #pragma unroll
  for (int ks = 0; ks < 16; ++ks) {
    bf16x8 a[4];
    #pragma unroll
    for (int rt = 0; rt < 4; ++rt)
      a[rt] = *(const bf16x8*)(mid + ((size_t)x0 + rt * 16 + lr) * DFFN + ks * 32 + lg * 8);
    bf16x8 bh[2], bl[2];
    #pragma unroll
    for (int dj = 0; dj < 2; ++dj) {
      size_t widx = (size_t)(d0 + dj * 16 + lr) * DFFN + ks * 32 + lg * 8;
      bh[dj] = *(const bf16x8*)(f2T_hi + widx);
      bl[dj] = *(const bf16x8*)(f2T_lo + widx);
    }
    #pragma unroll
    for (int dj = 0; dj < 2; ++dj)
      #pragma unroll
      for (int rt = 0; rt < 4; ++rt) {
        acc[rt][dj] = __builtin_amdgcn_mfma_f32_16x16x32_bf16(a[rt], bh[dj], acc[rt][dj], 0, 0, 0);
        acc[rt][dj] = __builtin_amdgcn_mfma_f32_16x16x32_bf16(a[rt], bl[dj], acc[rt][dj], 0, 0, 0);
      }
  }
  #pragma unroll
  for (int dj = 0; dj < 2; ++dj) {
    int d = d0 + dj * 16 + lr;
    float bb = b2[d];
    #pragma unroll
    for (int rt = 0; rt < 4; ++rt)
      #pragma unroll
      for (int r = 0; r < 4; ++r) {
        int rowl = rt * 16 + lg * 4 + r;
        float v = h[((size_t)x0 + rowl) * DD + d] + acc[rt][dj][r] + bb;
        h[((size_t)x0 + rowl) * DD + d] = v;
        T[d][rowl] = v;
      }
  }
  __syncthreads();
  for (int it = 0; it < 32; ++it) {
    int eid = it * 256 + tid; int d = eid >> 6, xl = eid & 63;
    float v = T[d][xl] * wls[xl];
    bf16 hi, lo; split2(v, hi, lo);
    size_t idx = ((size_t)b * DD + d) * NN + xb + xl;
    hw_hi[idx] = hi; hw_lo[idx] = lo;
  }
}

// ---------------- final LN + out proj (f32 out) ----------------
__global__ void k_out(const float* __restrict__ h, const float* __restrict__ lw,
                      const float* __restrict__ lb, const float* __restrict__ ow,
                      const float* __restrict__ ob, float* __restrict__ out) {
  int row = blockIdx.x; int tid = threadIdx.x;
  float v = h[(size_t)row * DD + tid];
  float s = v, q = v * v;
  for (int off = 32; off; off >>= 1) { s += __shfl_xor(s, off); q += __shfl_xor(q, off); }
  __shared__ float sh[4];
  __shared__ float sp[4];
  int wv = tid >> 6;
  if ((tid & 63) == 0) { sh[wv] = s; sh[2 + wv] = q; }
  __syncthreads();
  s = sh[0] + sh[1]; q = sh[2] + sh[3];
  float mean = s / 128.f, var = q / 128.f - mean * mean;
  float inv = rsqrtf(var + 1e-5f);
  float ln = (v - mean) * inv * lw[tid] + lb[tid];
  float p0 = ln * ow[tid * 2 + 0], p1 = ln * ow[tid * 2 + 1];
  for (int off = 32; off; off >>= 1) { p0 += __shfl_xor(p0, off); p1 += __shfl_xor(p1, off); }
  if ((tid & 63) == 0) { sp[wv] = p0; sp[2 + wv] = p1; }
  __syncthreads();
  if (tid == 0) out[(size_t)row * 2 + 0] = sp[0] + sp[1] + ob[0];
  if (tid == 1) out[(size_t)row * 2 + 1] = sp[2] + sp[3] + ob[1];
}

extern "C" void kernel_launch(void* const* d_in, const int* in_sizes, int n_in,
                              void* d_out, int out_size, void* d_ws, size_t ws_size,
                              hipStream_t stream) {
  const float* u      = (const float*)d_in[0];
  const float* nodes  = (const float*)d_in[1];
  const float* nw     = (const float*)d_in[2];
  const float* modes  = (const float*)d_in[3];
  const float* coordB = (const float*)d_in[4];
  const float* cp_w   = (const float*)d_in[5];
  const float* cp_b   = (const float*)d_in[6];
  const float* in_w   = (const float*)d_in[7];
  const float* in_b   = (const float*)d_in[8];
  const float* ln1_w  = (const float*)d_in[9];
  const float* ln1_b  = (const float*)d_in[10];
  const float* qkv_w  = (const float*)d_in[11];
  const float* qkv_b  = (const float*)d_in[12];
  const float* ao_w   = (const float*)d_in[13];
  const float* ao_b   = (const float*)d_in[14];
  const float* f1_w   = (const float*)d_in[15];
  const float* f1_b   = (const float*)d_in[16];
  const float* f2_w   = (const float*)d_in[17];
  const float* f2_b   = (const float*)d_in[18];
  const float* ln2_w  = (const float*)d_in[19];
  const float* ln2_b  = (const float*)d_in[20];
  const float* lnf_w  = (const float*)d_in[21];
  const float* lnf_b  = (const float*)d_in[22];
  const float* out_w  = (const float*)d_in[23];
  const float* out_b  = (const float*)d_in[24];

  char* ws = (char*)d_ws;
  size_t off = 0;
  bf16* bT    = (bf16*)(ws + off); off += (size_t)BB * TPAD * NN * 2;   // 41.9 MB
  bf16* bR    = (bf16*)(ws + off); off += (size_t)BB * NN * TPAD * 2;   // 41.9 MB
  float* h    = (float*)(ws + off); off += (size_t)BB * NN * DD * 4;    // 33.6 MB
  bf16* hw_hi = (bf16*)(ws + off); off += (size_t)BB * DD * NN * 2;     // 16.8 MB
  bf16* hw_lo = (bf16*)(ws + off); off += (size_t)BB * DD * NN * 2;     // 16.8 MB
  bf16* ln2h  = (bf16*)(ws + off); off += (size_t)BB * NN * DD * 2;     // 16.8 MB
  char* regMid = ws + off; off += (size_t)BB * NN * DFFN * 2;           // 67.1 MB
  float* partialT = (float*)regMid;                       // live: slice -> reduce
  bf16*  mid      = (bf16*)regMid;                        // live: ffnA -> ffnB
  float* qb  = (float*)(regMid + 40 * 1024 * 1024);       // live: qkv -> att
  float* kb  = qb  + (size_t)BB * MM * DD;
  float* vb  = kb  + (size_t)BB * MM * DD;
  float* ob2 = vb  + (size_t)BB * MM * DD;                // live: att -> ao
  float* Z    = (float*)(ws + off); off += (size_t)BB * MM * DD * 4;
  bf16* Zt    = (bf16*)(ws + off); off += (size_t)BB * DD * TPAD * 2;
  bf16* f1T_hi = (bf16*)(ws + off); off += (size_t)LL * DFFN * DD * 2;
  bf16* f1T_lo = (bf16*)(ws + off); off += (size_t)LL * DFFN * DD * 2;
  bf16* f2T_hi = (bf16*)(ws + off); off += (size_t)LL * DD * DFFN * 2;
  bf16* f2T_lo = (bf16*)(ws + off); off += (size_t)LL * DD * DFFN * 2;
  // total ~238.8 MB

  k_prepW<<<(2 * LL * DFFN * DD + 255) / 256, 256, 0, stream>>>(f1_w, f2_w, f1T_hi, f1T_lo, f2T_hi, f2T_lo);
  k_embed<<<BB * NN / 64, 256, 0, stream>>>(u, nodes, coordB, cp_w, cp_b, in_w, in_b, h);
  k_basesT<<<dim3(NN / 256, TPAD, BB), 256, 0, stream>>>(nodes, modes, bT);
  k_basesR<<<BB * NN, TPAD, 0, stream>>>(nodes, modes, bR);
  k_hTw<<<dim3(NN / 64, BB), 256, 0, stream>>>(h, nw, hw_hi, hw_lo);
  k_ztpad<<<(BB * DD * (TPAD - MM) + 255) / 256, 256, 0, stream>>>(Zt);

  for (int l = 0; l < LL; l++) {
    k_slice<<<dim3(SKC, TPAD / 64, BB), 256, 0, stream>>>(bT, hw_hi, hw_lo, partialT);
    k_reduce<<<(BB * DD * MM + 255) / 256, 256, 0, stream>>>(partialT, Z);
    k_qkv<<<BB * MM, 384, 0, stream>>>(Z, ln1_w + l * DD, ln1_b + l * DD,
                                       qkv_w + (size_t)l * DD * 3 * DD, qkv_b + l * 3 * DD, qb, kb, vb);
    k_att<<<dim3(9, BB * HHD), 256, 0, stream>>>(qb, kb, vb, ob2);
    k_ao<<<BB * MM, 128, 0, stream>>>(ob2, ao_w + (size_t)l * DD * DD, ao_b + l * DD, Z, Zt);
    k_deslice<<<dim3(NN / 64, BB), 256, 0, stream>>>(bR, Zt,
                                                     ln2_w + l * DD, ln2_b + l * DD, h, ln2h);
    k_ffnA<<<BB * NN / 64, 256, 0, stream>>>(ln2h, f1T_hi + (size_t)l * DFFN * DD,
                                             f1T_lo + (size_t)l * DFFN * DD, f1_b + l * DFFN, mid);
    k_ffnB<<<BB * NN / 64, 256, 0, stream>>>(mid, f2T_hi + (size_t)l * DD * DFFN,
                                             f2T_lo + (size_t)l * DD * DFFN, f2_b + l * DD,
                                             nw, h, hw_hi, hw_lo);
  }
  k_out<<<BB * NN, 128, 0, stream>>>(h, lnf_w, lnf_b, out_w, out_b, (float*)d_out);
}

// Round 16
// 1708.535 us; speedup vs baseline: 1.2853x; 1.0450x over previous
//
#include <hip/hip_runtime.h>
#include <hip/hip_bf16.h>
#include <math.h>

#define BB 4
#define NN 16384
#define KM 128
#define DD 128
#define HHD 8
#define LL 6
#define DFFN 512
#define NFF 16
#define DCC 64
#define MM 257
#define DHH 16
#define SKC 32      // split-K chunks for slice
#define TPAD 320    // t-dim padded

typedef __hip_bfloat16 bf16;
using bf16x8 = __attribute__((ext_vector_type(8))) short;
using f32x4  = __attribute__((ext_vector_type(4))) float;

__device__ __forceinline__ void split2(float v, bf16& hi, bf16& lo) {
  hi = __float2bfloat16(v);
  lo = __float2bfloat16(v - __bfloat162float(hi));
}
__device__ __forceinline__ short b2s(bf16 x) {
  union { bf16 b; short s; } u; u.b = x; return u.s;
}

// ---------------- prep: bf16 hi/lo transposed FFN weights ----------------
__global__ void k_prepW(const float* __restrict__ f1_w, const float* __restrict__ f2_w,
                        bf16* __restrict__ f1T_hi, bf16* __restrict__ f1T_lo,
                        bf16* __restrict__ f2T_hi, bf16* __restrict__ f2T_lo) {
  size_t i = (size_t)blockIdx.x * 256 + threadIdx.x;
  size_t n = (size_t)LL * DFFN * DD;
  if (i < n) {
    int l = i / (DFFN * DD); int rem = i % (DFFN * DD); int f = rem / DD; int d = rem % DD;
    bf16 hi, lo; split2(f1_w[(size_t)l * DD * DFFN + (size_t)d * DFFN + f], hi, lo);
    f1T_hi[i] = hi; f1T_lo[i] = lo;
  } else if (i < 2 * n) {
    size_t j = i - n;
    int l = j / (DD * DFFN); int rem = j % (DD * DFFN); int d = rem / DFFN; int f = rem % DFFN;
    bf16 hi, lo; split2(f2_w[(size_t)l * DFFN * DD + (size_t)f * DD + d], hi, lo);
    f2T_hi[j] = hi; f2T_lo[j] = lo;
  }
}

// ------- embed v4: 64 pts/block, weights+feats+hin in LDS, 3 barriers -------
__global__ void __launch_bounds__(256)
k_embed(const float* __restrict__ u, const float* __restrict__ nodes,
        const float* __restrict__ coordB,
        const float* __restrict__ cp_w, const float* __restrict__ cp_b,
        const float* __restrict__ in_w, const float* __restrict__ in_b,
        float* __restrict__ h) {
  int p0 = blockIdx.x * 64;
  int tid = threadIdx.x;
  __shared__ float w_in[66][128];   // 33.8 KB
  __shared__ float w_cp[34][64];    // 8.7 KB
  __shared__ float feats[64][34];   // 8.7 KB
  __shared__ float hin[64][68];     // 17.4 KB
  for (int i = tid; i < 66 * 128; i += 256) w_in[i >> 7][i & 127] = in_w[i];
  for (int i = tid; i < 34 * 64; i += 256) w_cp[i >> 6][i & 63] = cp_w[i];
  #pragma unroll
  for (int it = 0; it < 4; ++it) {
    int i = it * 256 + tid; int p = i >> 4, f = i & 15;
    float n0 = nodes[(size_t)(p0 + p) * 2 + 0], n1 = nodes[(size_t)(p0 + p) * 2 + 1];
    float xb = n0 * coordB[f] + n1 * coordB[NFF + f];
    feats[p][2 + f] = sinf(xb);
    feats[p][2 + NFF + f] = cosf(xb);
    if (f == 0) {
      feats[p][0] = n0; feats[p][1] = n1;
      hin[p][0] = u[(size_t)(p0 + p) * 2 + 0];
      hin[p][1] = u[(size_t)(p0 + p) * 2 + 1];
    }
  }
  __syncthreads();
  #pragma unroll
  for (int it = 0; it < 16; ++it) {
    int j = it * 256 + tid; int p = j >> 6, cc = j & 63;
    float acc = cp_b[cc];
    #pragma unroll
    for (int i = 0; i < 34; ++i) acc += feats[p][i] * w_cp[i][cc];
    hin[p][2 + cc] = acc;
  }
  __syncthreads();
  #pragma unroll
  for (int it = 0; it < 32; ++it) {
    int j = it * 256 + tid; int p = j >> 7, d = j & 127;
    float acc = in_b[d];
    #pragma unroll
    for (int i = 0; i < 66; ++i) acc += hin[p][i] * w_in[i][d];
    h[(size_t)(p0 + p) * DD + d] = acc;
  }
}

__device__ __forceinline__ float basis_val(int t, float n0, float n1, const float* modes) {
  if (t >= 2 * KM) return (t == 2 * KM) ? 1.0f : 0.0f;
  int mi = t & (KM - 1);
  float th = n0 * modes[mi * 2 + 0] + n1 * modes[mi * 2 + 1];
  float s, c; __sincosf(th, &s, &c);
  return (t < KM) ? c : s;
}

// ---------------- basesT [b][t][x] single bf16 (slice B operand) ----------------
__global__ void k_basesT(const float* __restrict__ nodes, const float* __restrict__ modes,
                         bf16* __restrict__ bT) {
  int t = blockIdx.y, b = blockIdx.z;
  int x = blockIdx.x * 256 + threadIdx.x;
  float2 nd = *(const float2*)(nodes + ((size_t)b * NN + x) * 2);
  float v = basis_val(t, nd.x, nd.y, modes);
  bT[((size_t)b * TPAD + t) * NN + x] = __float2bfloat16(v);
}

// ---------------- basesR [b][x][t] single bf16 (deslice A operand) ----------------
__global__ void k_basesR(const float* __restrict__ nodes, const float* __restrict__ modes,
                         bf16* __restrict__ bR) {
  int p = blockIdx.x;          // b*N + x
  int t = threadIdx.x;         // 0..319
  float2 nd = *(const float2*)(nodes + (size_t)p * 2);
  float v = basis_val(t, nd.x, nd.y, modes);
  bR[(size_t)p * TPAD + t] = __float2bfloat16(v);
}

// ---------------- one-time: zero the Zt pad columns ----------------
__global__ void k_ztpad(bf16* __restrict__ Zt) {
  int i = blockIdx.x * 256 + threadIdx.x;
  int tot = BB * DD * (TPAD - MM);
  if (i >= tot) return;
  int bd = i / (TPAD - MM); int t = MM + i % (TPAD - MM);
  Zt[(size_t)bd * TPAD + t] = __float2bfloat16(0.f);
}

// ---------------- hTw init: [d][x] = h*w, single bf16 ----------------
__global__ void k_hTw(const float* __restrict__ h, const float* __restrict__ nw,
                      bf16* __restrict__ hw) {
  int xt = blockIdx.x, b = blockIdx.y; int x0 = xt * 64;
  __shared__ float T[128][67];
  __shared__ float wls[64];
  int tid = threadIdx.x;
  if (tid < 64) wls[tid] = nw[(size_t)b * NN + x0 + tid];
  for (int it = 0; it < 32; ++it) {
    int eid = it * 256 + tid; int x = eid >> 7, d = eid & 127;
    T[d][x] = h[((size_t)b * NN + x0 + x) * DD + d];
  }
  __syncthreads();
  for (int it = 0; it < 32; ++it) {
    int eid = it * 256 + tid; int d = eid >> 6, xl = eid & 63;
    float v = T[d][xl] * wls[xl];
    hw[((size_t)b * DD + d) * NN + x0 + xl] = __float2bfloat16(v);
  }
}

// ---------------- slice (MFMA, no LDS, single-bf16 A): partialT[b][ck][d][t] ----------------
__global__ void __launch_bounds__(256, 4)
k_slice(const bf16* __restrict__ bT, const bf16* __restrict__ hw,
        float* __restrict__ partialT) {
  int ck = blockIdx.x, tg = blockIdx.y, b = blockIdx.z;
  int kbase = ck * (NN / SKC);   // 512-chunk of x
  int tid = threadIdx.x, w = tid >> 6, lane = tid & 63, lr = lane & 15, lg = lane >> 4;
  const bf16* pA = hw + ((size_t)b * DD + w * 32 + lr) * NN + kbase + lg * 8;
  const bf16* pB = bT + ((size_t)b * TPAD + tg * 64 + lr) * NN + kbase + lg * 8;
  f32x4 acc[8];
  #pragma unroll
  for (int i = 0; i < 8; i++) acc[i] = (f32x4){0.f, 0.f, 0.f, 0.f};
  for (int kc = 0; kc < NN / SKC; kc += 64) {
    bf16x8 aa[2][2], bb[2][4];
    #pragma unroll
    for (int ks2 = 0; ks2 < 2; ++ks2) {
      int ko = kc + ks2 * 32;
      #pragma unroll
      for (int fi = 0; fi < 2; ++fi)
        aa[ks2][fi] = *(const bf16x8*)(pA + (size_t)fi * 16 * NN + ko);
      #pragma unroll
      for (int tc = 0; tc < 4; ++tc)
        bb[ks2][tc] = *(const bf16x8*)(pB + (size_t)tc * 16 * NN + ko);
    }
    #pragma unroll
    for (int ks2 = 0; ks2 < 2; ++ks2)
      #pragma unroll
      for (int fi = 0; fi < 2; ++fi)
        #pragma unroll
        for (int tc = 0; tc < 4; ++tc) {
          int ai = fi * 4 + tc;
          acc[ai] = __builtin_amdgcn_mfma_f32_16x16x32_bf16(aa[ks2][fi], bb[ks2][tc], acc[ai], 0, 0, 0);
        }
  }
  float* pp = partialT + ((size_t)(b * SKC + ck) * DD) * TPAD;
  #pragma unroll
  for (int fi = 0; fi < 2; ++fi)
    #pragma unroll
    for (int tc = 0; tc < 4; ++tc)
      #pragma unroll
      for (int r = 0; r < 4; ++r) {
        int d = w * 32 + fi * 16 + lg * 4 + r;
        int t = tg * 64 + tc * 16 + lr;
        pp[(size_t)d * TPAD + t] = acc[fi * 4 + tc][r];
      }
}

// ---------------- reduce: Z[t][d] = sum_ck partialT[ck][d][t] ----------------
__global__ void k_reduce(const float* __restrict__ partialT, float* __restrict__ Z) {
  int idx = blockIdx.x * 256 + threadIdx.x;
  if (idx >= BB * DD * MM) return;
  int b = idx / (DD * MM); int rem = idx % (DD * MM); int d = rem / MM; int t = rem % MM;
  float s = 0.f;
  #pragma unroll
  for (int ck = 0; ck < SKC; ck++)
    s += partialT[((size_t)(b * SKC + ck) * DD + d) * TPAD + t];
  Z[((size_t)b * MM + t) * DD + d] = s;
}

// ---------------- qkv (fused LN1) ----------------
__global__ void k_qkv(const float* __restrict__ Z, const float* __restrict__ lnw,
                      const float* __restrict__ lnb, const float* __restrict__ W,
                      const float* __restrict__ bias, float* __restrict__ q,
                      float* __restrict__ k, float* __restrict__ v) {
  int row = blockIdx.x;            // b*M + t
  int b = row / MM, t = row % MM;
  int j = threadIdx.x;             // 0..383
  __shared__ float zr[128];
  __shared__ float red[4];
  if (j < 128) {
    float val = Z[(size_t)row * DD + j];
    zr[j] = val;
    float s = val, q2 = val * val;
    for (int off = 32; off; off >>= 1) { s += __shfl_xor(s, off); q2 += __shfl_xor(q2, off); }
    if ((j & 63) == 0) { red[(j >> 6) * 2] = s; red[(j >> 6) * 2 + 1] = q2; }
  }
  __syncthreads();
  float s = red[0] + red[2], q2 = red[1] + red[3];
  float mean = s / 128.f;
  float var = q2 / 128.f - mean * mean;
  float inv = rsqrtf(var + 1e-5f);
  if (j < 128) zr[j] = (zr[j] - mean) * inv * lnw[j] + lnb[j];
  __syncthreads();
  float acc = bias[j];
  for (int i = 0; i < 128; i++) acc += zr[i] * W[(size_t)i * 384 + j];
  int which = j >> 7;
  int jj = j & 127;
  int hh = jj >> 4, dh = jj & 15;
  float* dst = (which == 0) ? q : (which == 1) ? k : v;
  dst[((size_t)(b * HHD + hh) * MM + t) * DHH + dh] = acc;
}

// ---------------- attention (split-KV, 8 segs/row, shfl merge) ----------------
__global__ void __launch_bounds__(256, 4)
k_att(const float* __restrict__ q, const float* __restrict__ k,
      const float* __restrict__ v, float* __restrict__ obuf) {
  int bh = blockIdx.y; int b = bh / HHD, hh = bh % HHD;
  int rt = blockIdx.x;             // 0..8, rows rt*32 .. rt*32+31
  __shared__ float ks[MM * DHH];
  __shared__ float vs[MM * DHH];
  const float* kp = k + (size_t)bh * MM * DHH;
  const float* vp = v + (size_t)bh * MM * DHH;
  for (int i = threadIdx.x; i < MM * DHH; i += 256) { ks[i] = kp[i]; vs[i] = vp[i]; }
  __syncthreads();
  const float scale = 0.25f;
  int tid = threadIdx.x;
  int row = rt * 32 + (tid >> 3);
  int seg = tid & 7;
  float m = -1e30f, s = 0.f, o[16];
  #pragma unroll
  for (int j = 0; j < 16; j++) o[j] = 0.f;
  if (row < MM) {
    float qr[16];
    const float* qp = q + ((size_t)bh * MM + row) * DHH;
    #pragma unroll
    for (int j = 0; j < 16; j++) qr[j] = qp[j];
    int t0 = seg * 33;
    int t1 = t0 + 33; if (t1 > MM) t1 = MM;
    for (int t = t0; t < t1; t++) {
      float sc = 0.f;
      #pragma unroll
      for (int j = 0; j < 16; j++) sc += qr[j] * ks[t * 16 + j];
      sc *= scale;
      float mn = fmaxf(m, sc);
      float corr = __expf(m - mn);
      float e = __expf(sc - mn);
      s = s * corr + e;
      #pragma unroll
      for (int j = 0; j < 16; j++) o[j] = o[j] * corr + e * vs[t * 16 + j];
      m = mn;
    }
  }
  #pragma unroll
  for (int off2 = 1; off2 < 8; off2 <<= 1) {
    float m2 = __shfl_xor(m, off2);
    float s2 = __shfl_xor(s, off2);
    float mn = fmaxf(m, m2);
    float c1 = __expf(m - mn), c2 = __expf(m2 - mn);
    s = s * c1 + s2 * c2;
    #pragma unroll
    for (int j = 0; j < 16; j++) o[j] = o[j] * c1 + __shfl_xor(o[j], off2) * c2;
    m = mn;
  }
  if (seg == 0 && row < MM) {
    float invs = 1.f / s;
    float* op = obuf + ((size_t)(b * MM + row)) * DD + hh * DHH;
    #pragma unroll
    for (int j4 = 0; j4 < 4; ++j4) {
      float4 vv = make_float4(o[j4 * 4] * invs, o[j4 * 4 + 1] * invs,
                              o[j4 * 4 + 2] * invs, o[j4 * 4 + 3] * invs);
      *(float4*)(op + j4 * 4) = vv;
    }
  }
}

// ---------------- attn out proj -> Zt single bf16 (fused zt) ----------------
__global__ void k_ao(const float* __restrict__ obuf, const float* __restrict__ W,
                     const float* __restrict__ bias, const float* __restrict__ Z,
                     bf16* __restrict__ Zt) {
  int row = blockIdx.x; int d = threadIdx.x;
  int b = row / MM, t = row % MM;
  __shared__ float orow[128];
  orow[d] = obuf[(size_t)row * DD + d];
  __syncthreads();
  float acc = bias[d];
  for (int i = 0; i < 128; i++) acc += orow[i] * W[(size_t)i * DD + d];
  float nz = Z[(size_t)row * DD + d] + acc;
  Zt[((size_t)b * DD + d) * TPAD + t] = __float2bfloat16(nz);
}

// ------- deslice (MFMA, pure global, single-bf16 Zt) + fused LN2 -> ln2h -------
__global__ void __launch_bounds__(256, 4)
k_deslice(const bf16* __restrict__ bR, const bf16* __restrict__ Zt,
          const float* __restrict__ lw, const float* __restrict__ lb,
          float* __restrict__ h, bf16* __restrict__ ln2h) {
  int xt = blockIdx.x, b = blockIdx.y;
  int x0 = xt * 64;
  int tid = threadIdx.x, w = tid >> 6, lane = tid & 63, lr = lane & 15, lg = lane >> 4;
  const bf16* pA = bR + ((size_t)b * NN + x0 + w * 16 + lr) * TPAD + lg * 8;
  const bf16* pB = Zt + ((size_t)b * DD + lr) * TPAD + lg * 8;
  f32x4 acc[8];
  #pragma unroll
  for (int i = 0; i < 8; i++) acc[i] = (f32x4){0.f, 0.f, 0.f, 0.f};
  for (int kc = 0; kc < TPAD; kc += 64) {
    #pragma unroll
    for (int ks2 = 0; ks2 < 2; ++ks2) {
      int ko = kc + ks2 * 32;
      bf16x8 a = *(const bf16x8*)(pA + ko);
      bf16x8 bb[8];
      #pragma unroll
      for (int fi = 0; fi < 8; ++fi)
        bb[fi] = *(const bf16x8*)(pB + (size_t)fi * 16 * TPAD + ko);
      #pragma unroll
      for (int fi = 0; fi < 8; ++fi)
        acc[fi] = __builtin_amdgcn_mfma_f32_16x16x32_bf16(a, bb[fi], acc[fi], 0, 0, 0);
    }
  }
  float lwv[8], lbv[8];
  #pragma unroll
  for (int fi = 0; fi < 8; ++fi) { lwv[fi] = lw[fi * 16 + lr]; lbv[fi] = lb[fi * 16 + lr]; }
  float hv[8][4];
  float sm[4], sq[4];
  #pragma unroll
  for (int r = 0; r < 4; ++r) { sm[r] = 0.f; sq[r] = 0.f; }
  size_t rowbase = ((size_t)b * NN + x0 + w * 16 + lg * 4);
  #pragma unroll
  for (int fi = 0; fi < 8; ++fi)
    #pragma unroll
    for (int r = 0; r < 4; ++r) {
      float v = h[(rowbase + r) * DD + fi * 16 + lr] + acc[fi][r];
      hv[fi][r] = v; sm[r] += v; sq[r] += v * v;
    }
  #pragma unroll
  for (int r = 0; r < 4; ++r) {
    float s = sm[r], q = sq[r];
    s += __shfl_xor(s, 1); q += __shfl_xor(q, 1);
    s += __shfl_xor(s, 2); q += __shfl_xor(q, 2);
    s += __shfl_xor(s, 4); q += __shfl_xor(q, 4);
    s += __shfl_xor(s, 8); q += __shfl_xor(q, 8);
    float mean = s / 128.f;
    float var = q / 128.f - mean * mean;
    sm[r] = mean; sq[r] = rsqrtf(var + 1e-5f);
  }
  #pragma unroll
  for (int fi = 0; fi < 8; ++fi)
    #pragma unroll
    for (int r = 0; r < 4; ++r) {
      float v = hv[fi][r];
      h[(rowbase + r) * DD + fi * 16 + lr] = v;
      float ln = (v - sm[r]) * sq[r] * lwv[fi] + lbv[fi];
      ln2h[(rowbase + r) * DD + fi * 16 + lr] = __float2bfloat16(ln);
    }
}

// ------- ffnA (MFMA, 64-row blocks): mid = gelu(ln2h @ f1 + b1) bf16 -------
__global__ void __launch_bounds__(256, 2)
k_ffnA(const bf16* __restrict__ ln2h, const bf16* __restrict__ f1T_hi,
       const bf16* __restrict__ f1T_lo, const float* __restrict__ b1,
       bf16* __restrict__ mid) {
  int x0 = blockIdx.x * 64;
  int tid = threadIdx.x, w = tid >> 6, lane = tid & 63, lr = lane & 15, lg = lane >> 4;
  int f0 = w * 128;
  __shared__ short mid_s[16][DFFN + 8];
  f32x4 acc[4][8];
  #pragma unroll
  for (int rt = 0; rt < 4; ++rt)
    #pragma unroll
    for (int fi = 0; fi < 8; ++fi) acc[rt][fi] = (f32x4){0.f, 0.f, 0.f, 0.f};
  #pragma unroll
  for (int ks = 0; ks < 4; ++ks) {
    bf16x8 a[4];
    #pragma unroll
    for (int rt = 0; rt < 4; ++rt)
      a[rt] = *(const bf16x8*)(ln2h + ((size_t)x0 + rt * 16 + lr) * DD + ks * 32 + lg * 8);
    bf16x8 bh[8];
    #pragma unroll
    for (int fi = 0; fi < 8; ++fi)
      bh[fi] = *(const bf16x8*)(f1T_hi + (size_t)(f0 + fi * 16 + lr) * DD + ks * 32 + lg * 8);
    #pragma unroll
    for (int fi = 0; fi < 8; ++fi)
      #pragma unroll
      for (int rt = 0; rt < 4; ++rt)
        acc[rt][fi] = __builtin_amdgcn_mfma_f32_16x16x32_bf16(a[rt], bh[fi], acc[rt][fi], 0, 0, 0);
    bf16x8 bl[8];
    #pragma unroll
    for (int fi = 0; fi < 8; ++fi)
      bl[fi] = *(const bf16x8*)(f1T_lo + (size_t)(f0 + fi * 16 + lr) * DD + ks * 32 + lg * 8);
    #pragma unroll
    for (int fi = 0; fi < 8; ++fi)
      #pragma unroll
      for (int rt = 0; rt < 4; ++rt)
        acc[rt][fi] = __builtin_amdgcn_mfma_f32_16x16x32_bf16(a[rt], bl[fi], acc[rt][fi], 0, 0, 0);
  }
  #pragma unroll
  for (int rt = 0; rt < 4; ++rt) {
    __syncthreads();
    #pragma unroll
    for (int fi = 0; fi < 8; ++fi) {
      int col = f0 + fi * 16 + lr;
      float bb = b1[col];
      #pragma unroll
      for (int r = 0; r < 4; ++r) {
        float xx = acc[rt][fi][r] + bb;
        float gl = 0.5f * xx * (1.f + erff(xx * 0.70710678118654752f));
        mid_s[lg * 4 + r][col] = b2s(__float2bfloat16(gl));
      }
    }
    __syncthreads();
    #pragma unroll
    for (int it = 0; it < 4; ++it) {
      int eid = it * 256 + tid;
      int row = eid >> 6, c = eid & 63;
      uint4 vv = *(const uint4*)&mid_s[row][c * 8];
      *(uint4*)(mid + ((size_t)x0 + rt * 16 + row) * DFFN + c * 8) = vv;
    }
  }
}

// ------- ffnB (MFMA): wave owns 32 d-cols x all 64 rows; h += mid@f2 + b2 -------
__global__ void __launch_bounds__(256, 2)
k_ffnB(const bf16* __restrict__ mid, const bf16* __restrict__ f2T_hi,
       const bf16* __restrict__ f2T_lo, const float* __restrict__ b2,
       const float* __restrict__ nw, float* __restrict__ h,
       bf16* __restrict__ hw) {
  int x0 = blockIdx.x * 64;
  int b = x0 / NN; int xb = x0 % NN;
  int tid = threadIdx.x, w = tid >> 6, lane = tid & 63, lr = lane & 15, lg = lane >> 4;
  int d0 = w * 32;
  __shared__ float T[128][67];
  __shared__ float wls[64];
  if (tid < 64) wls[tid] = nw[(size_t)b * NN + xb + tid];
  f32x4 acc[4][2];
  #pragma unroll
  for (int rt = 0; rt < 4; ++rt)
    #pragma unroll
    for (int dj = 0; dj < 2; ++dj) acc[rt][dj] = (f32x4){0.f, 0.f, 0.f, 0.f};
  #pragma unroll
  for (int ks = 0; ks < 16; ++ks) {
    bf16x8 a[4];
    #pragma unroll
    for (int rt = 0; rt < 4; ++rt)
      a[rt] = *(const bf16x8*)(mid + ((size_t)x0 + rt * 16 + lr) * DFFN + ks * 32 + lg * 8);
    bf16x8 bh[2], bl[2];
    #pragma unroll
    for (int dj = 0; dj < 2; ++dj) {
      size_t widx = (size_t)(d0 + dj * 16 + lr) * DFFN + ks * 32 + lg * 8;
      bh[dj] = *(const bf16x8*)(f2T_hi + widx);
      bl[dj] = *(const bf16x8*)(f2T_lo + widx);
    }
    #pragma unroll
    for (int dj = 0; dj < 2; ++dj)
      #pragma unroll
      for (int rt = 0; rt < 4; ++rt) {
        acc[rt][dj] = __builtin_amdgcn_mfma_f32_16x16x32_bf16(a[rt], bh[dj], acc[rt][dj], 0, 0, 0);
        acc[rt][dj] = __builtin_amdgcn_mfma_f32_16x16x32_bf16(a[rt], bl[dj], acc[rt][dj], 0, 0, 0);
      }
  }
  #pragma unroll
  for (int dj = 0; dj < 2; ++dj) {
    int d = d0 + dj * 16 + lr;
    float bb = b2[d];
    #pragma unroll
    for (int rt = 0; rt < 4; ++rt)
      #pragma unroll
      for (int r = 0; r < 4; ++r) {
        int rowl = rt * 16 + lg * 4 + r;
        float v = h[((size_t)x0 + rowl) * DD + d] + acc[rt][dj][r] + bb;
        h[((size_t)x0 + rowl) * DD + d] = v;
        T[d][rowl] = v;
      }
  }
  __syncthreads();
  for (int it = 0; it < 32; ++it) {
    int eid = it * 256 + tid; int d = eid >> 6, xl = eid & 63;
    float v = T[d][xl] * wls[xl];
    hw[((size_t)b * DD + d) * NN + xb + xl] = __float2bfloat16(v);
  }
}

// ---------------- final LN + out proj (f32 out) ----------------
__global__ void k_out(const float* __restrict__ h, const float* __restrict__ lw,
                      const float* __restrict__ lb, const float* __restrict__ ow,
                      const float* __restrict__ ob, float* __restrict__ out) {
  int row = blockIdx.x; int tid = threadIdx.x;
  float v = h[(size_t)row * DD + tid];
  float s = v, q = v * v;
  for (int off = 32; off; off >>= 1) { s += __shfl_xor(s, off); q += __shfl_xor(q, off); }
  __shared__ float sh[4];
  __shared__ float sp[4];
  int wv = tid >> 6;
  if ((tid & 63) == 0) { sh[wv] = s; sh[2 + wv] = q; }
  __syncthreads();
  s = sh[0] + sh[1]; q = sh[2] + sh[3];
  float mean = s / 128.f, var = q / 128.f - mean * mean;
  float inv = rsqrtf(var + 1e-5f);
  float ln = (v - mean) * inv * lw[tid] + lb[tid];
  float p0 = ln * ow[tid * 2 + 0], p1 = ln * ow[tid * 2 + 1];
  for (int off = 32; off; off >>= 1) { p0 += __shfl_xor(p0, off); p1 += __shfl_xor(p1, off); }
  if ((tid & 63) == 0) { sp[wv] = p0; sp[2 + wv] = p1; }
  __syncthreads();
  if (tid == 0) out[(size_t)row * 2 + 0] = sp[0] + sp[1] + ob[0];
  if (tid == 1) out[(size_t)row * 2 + 1] = sp[2] + sp[3] + ob[1];
}

extern "C" void kernel_launch(void* const* d_in, const int* in_sizes, int n_in,
                              void* d_out, int out_size, void* d_ws, size_t ws_size,
                              hipStream_t stream) {
  const float* u      = (const float*)d_in[0];
  const float* nodes  = (const float*)d_in[1];
  const float* nw     = (const float*)d_in[2];
  const float* modes  = (const float*)d_in[3];
  const float* coordB = (const float*)d_in[4];
  const float* cp_w   = (const float*)d_in[5];
  const float* cp_b   = (const float*)d_in[6];
  const float* in_w   = (const float*)d_in[7];
  const float* in_b   = (const float*)d_in[8];
  const float* ln1_w  = (const float*)d_in[9];
  const float* ln1_b  = (const float*)d_in[10];
  const float* qkv_w  = (const float*)d_in[11];
  const float* qkv_b  = (const float*)d_in[12];
  const float* ao_w   = (const float*)d_in[13];
  const float* ao_b   = (const float*)d_in[14];
  const float* f1_w   = (const float*)d_in[15];
  const float* f1_b   = (const float*)d_in[16];
  const float* f2_w   = (const float*)d_in[17];
  const float* f2_b   = (const float*)d_in[18];
  const float* ln2_w  = (const float*)d_in[19];
  const float* ln2_b  = (const float*)d_in[20];
  const float* lnf_w  = (const float*)d_in[21];
  const float* lnf_b  = (const float*)d_in[22];
  const float* out_w  = (const float*)d_in[23];
  const float* out_b  = (const float*)d_in[24];

  char* ws = (char*)d_ws;
  size_t off = 0;
  bf16* bT    = (bf16*)(ws + off); off += (size_t)BB * TPAD * NN * 2;   // 41.9 MB
  bf16* bR    = (bf16*)(ws + off); off += (size_t)BB * NN * TPAD * 2;   // 41.9 MB
  float* h    = (float*)(ws + off); off += (size_t)BB * NN * DD * 4;    // 33.6 MB
  bf16* hw    = (bf16*)(ws + off); off += (size_t)BB * DD * NN * 2;     // 16.8 MB
  bf16* ln2h  = (bf16*)(ws + off); off += (size_t)BB * NN * DD * 2;     // 16.8 MB
  char* regMid = ws + off; off += (size_t)BB * NN * DFFN * 2;           // 67.1 MB
  float* partialT = (float*)regMid;                       // live: slice -> reduce
  bf16*  mid      = (bf16*)regMid;                        // live: ffnA -> ffnB
  float* qb  = (float*)(regMid + 40 * 1024 * 1024);       // live: qkv -> att
  float* kb  = qb  + (size_t)BB * MM * DD;
  float* vb  = kb  + (size_t)BB * MM * DD;
  float* ob2 = vb  + (size_t)BB * MM * DD;                // live: att -> ao
  float* Z    = (float*)(ws + off); off += (size_t)BB * MM * DD * 4;
  bf16* Zt    = (bf16*)(ws + off); off += (size_t)BB * DD * TPAD * 2;
  bf16* f1T_hi = (bf16*)(ws + off); off += (size_t)LL * DFFN * DD * 2;
  bf16* f1T_lo = (bf16*)(ws + off); off += (size_t)LL * DFFN * DD * 2;
  bf16* f2T_hi = (bf16*)(ws + off); off += (size_t)LL * DD * DFFN * 2;
  bf16* f2T_lo = (bf16*)(ws + off); off += (size_t)LL * DD * DFFN * 2;
  // total ~222 MB

  k_prepW<<<(2 * LL * DFFN * DD + 255) / 256, 256, 0, stream>>>(f1_w, f2_w, f1T_hi, f1T_lo, f2T_hi, f2T_lo);
  k_embed<<<BB * NN / 64, 256, 0, stream>>>(u, nodes, coordB, cp_w, cp_b, in_w, in_b, h);
  k_basesT<<<dim3(NN / 256, TPAD, BB), 256, 0, stream>>>(nodes, modes, bT);
  k_basesR<<<BB * NN, TPAD, 0, stream>>>(nodes, modes, bR);
  k_hTw<<<dim3(NN / 64, BB), 256, 0, stream>>>(h, nw, hw);
  k_ztpad<<<(BB * DD * (TPAD - MM) + 255) / 256, 256, 0, stream>>>(Zt);

  for (int l = 0; l < LL; l++) {
    k_slice<<<dim3(SKC, TPAD / 64, BB), 256, 0, stream>>>(bT, hw, partialT);
    k_reduce<<<(BB * DD * MM + 255) / 256, 256, 0, stream>>>(partialT, Z);
    k_qkv<<<BB * MM, 384, 0, stream>>>(Z, ln1_w + l * DD, ln1_b + l * DD,
                                       qkv_w + (size_t)l * DD * 3 * DD, qkv_b + l * 3 * DD, qb, kb, vb);
    k_att<<<dim3(9, BB * HHD), 256, 0, stream>>>(qb, kb, vb, ob2);
    k_ao<<<BB * MM, 128, 0, stream>>>(ob2, ao_w + (size_t)l * DD * DD, ao_b + l * DD, Z, Zt);
    k_deslice<<<dim3(NN / 64, BB), 256, 0, stream>>>(bR, Zt,
                                                     ln2_w + l * DD, ln2_b + l * DD, h, ln2h);
    k_ffnA<<<BB * NN / 64, 256, 0, stream>>>(ln2h, f1T_hi + (size_t)l * DFFN * DD,
                                             f1T_lo + (size_t)l * DFFN * DD, f1_b + l * DFFN, mid);
    k_ffnB<<<BB * NN / 64, 256, 0, stream>>>(mid, f2T_hi + (size_t)l * DD * DFFN,
                                             f2T_lo + (size_t)l * DD * DFFN, f2_b + l * DD,
                                             nw, h, hw);
  }
  k_out<<<BB * NN, 128, 0, stream>>>(h, lnf_w, lnf_b, out_w, out_b, (float*)d_out);
}

// Round 17
// 1543.748 us; speedup vs baseline: 1.4225x; 1.1067x over previous
//
#include <hip/hip_runtime.h>
#include <hip/hip_bf16.h>
#include <math.h>

#define BB 4
#define NN 16384
#define KM 128
#define DD 128
#define HHD 8
#define LL 6
#define DFFN 512
#define NFF 16
#define DCC 64
#define MM 257
#define DHH 16
#define SKC 32      // split-K chunks for slice
#define TPAD 320    // t-dim padded

typedef __hip_bfloat16 bf16;
using bf16x8 = __attribute__((ext_vector_type(8))) short;
using f32x4  = __attribute__((ext_vector_type(4))) float;

__device__ __forceinline__ short b2s(bf16 x) {
  union { bf16 b; short s; } u; u.b = x; return u.s;
}

// ---------------- prep: bf16 transposed FFN weights (single) ----------------
__global__ void k_prepW(const float* __restrict__ f1_w, const float* __restrict__ f2_w,
                        bf16* __restrict__ f1T, bf16* __restrict__ f2T) {
  size_t i = (size_t)blockIdx.x * 256 + threadIdx.x;
  size_t n = (size_t)LL * DFFN * DD;
  if (i < n) {
    int l = i / (DFFN * DD); int rem = i % (DFFN * DD); int f = rem / DD; int d = rem % DD;
    f1T[i] = __float2bfloat16(f1_w[(size_t)l * DD * DFFN + (size_t)d * DFFN + f]);
  } else if (i < 2 * n) {
    size_t j = i - n;
    int l = j / (DD * DFFN); int rem = j % (DD * DFFN); int d = rem / DFFN; int f = rem % DFFN;
    f2T[j] = __float2bfloat16(f2_w[(size_t)l * DFFN * DD + (size_t)f * DD + d]);
  }
}

// ------- embed v4: 64 pts/block, weights+feats+hin in LDS, 3 barriers -------
__global__ void __launch_bounds__(256)
k_embed(const float* __restrict__ u, const float* __restrict__ nodes,
        const float* __restrict__ coordB,
        const float* __restrict__ cp_w, const float* __restrict__ cp_b,
        const float* __restrict__ in_w, const float* __restrict__ in_b,
        float* __restrict__ h) {
  int p0 = blockIdx.x * 64;
  int tid = threadIdx.x;
  __shared__ float w_in[66][128];   // 33.8 KB
  __shared__ float w_cp[34][64];    // 8.7 KB
  __shared__ float feats[64][34];   // 8.7 KB
  __shared__ float hin[64][68];     // 17.4 KB
  for (int i = tid; i < 66 * 128; i += 256) w_in[i >> 7][i & 127] = in_w[i];
  for (int i = tid; i < 34 * 64; i += 256) w_cp[i >> 6][i & 63] = cp_w[i];
  #pragma unroll
  for (int it = 0; it < 4; ++it) {
    int i = it * 256 + tid; int p = i >> 4, f = i & 15;
    float n0 = nodes[(size_t)(p0 + p) * 2 + 0], n1 = nodes[(size_t)(p0 + p) * 2 + 1];
    float xb = n0 * coordB[f] + n1 * coordB[NFF + f];
    feats[p][2 + f] = sinf(xb);
    feats[p][2 + NFF + f] = cosf(xb);
    if (f == 0) {
      feats[p][0] = n0; feats[p][1] = n1;
      hin[p][0] = u[(size_t)(p0 + p) * 2 + 0];
      hin[p][1] = u[(size_t)(p0 + p) * 2 + 1];
    }
  }
  __syncthreads();
  #pragma unroll
  for (int it = 0; it < 16; ++it) {
    int j = it * 256 + tid; int p = j >> 6, cc = j & 63;
    float acc = cp_b[cc];
    #pragma unroll
    for (int i = 0; i < 34; ++i) acc += feats[p][i] * w_cp[i][cc];
    hin[p][2 + cc] = acc;
  }
  __syncthreads();
  #pragma unroll
  for (int it = 0; it < 32; ++it) {
    int j = it * 256 + tid; int p = j >> 7, d = j & 127;
    float acc = in_b[d];
    #pragma unroll
    for (int i = 0; i < 66; ++i) acc += hin[p][i] * w_in[i][d];
    h[(size_t)(p0 + p) * DD + d] = acc;
  }
}

__device__ __forceinline__ float basis_val(int t, float n0, float n1, const float* modes) {
  if (t >= 2 * KM) return (t == 2 * KM) ? 1.0f : 0.0f;
  int mi = t & (KM - 1);
  float th = n0 * modes[mi * 2 + 0] + n1 * modes[mi * 2 + 1];
  float s, c; __sincosf(th, &s, &c);
  return (t < KM) ? c : s;
}

// ---------------- basesT [b][t][x] single bf16 (slice B operand) ----------------
__global__ void k_basesT(const float* __restrict__ nodes, const float* __restrict__ modes,
                         bf16* __restrict__ bT) {
  int t = blockIdx.y, b = blockIdx.z;
  int x = blockIdx.x * 256 + threadIdx.x;
  float2 nd = *(const float2*)(nodes + ((size_t)b * NN + x) * 2);
  float v = basis_val(t, nd.x, nd.y, modes);
  bT[((size_t)b * TPAD + t) * NN + x] = __float2bfloat16(v);
}

// ---------------- basesR [b][x][t] single bf16 (deslice A operand) ----------------
__global__ void k_basesR(const float* __restrict__ nodes, const float* __restrict__ modes,
                         bf16* __restrict__ bR) {
  int p = blockIdx.x;          // b*N + x
  int t = threadIdx.x;         // 0..319
  float2 nd = *(const float2*)(nodes + (size_t)p * 2);
  float v = basis_val(t, nd.x, nd.y, modes);
  bR[(size_t)p * TPAD + t] = __float2bfloat16(v);
}

// ---------------- one-time: zero the Zt pad columns ----------------
__global__ void k_ztpad(bf16* __restrict__ Zt) {
  int i = blockIdx.x * 256 + threadIdx.x;
  int tot = BB * DD * (TPAD - MM);
  if (i >= tot) return;
  int bd = i / (TPAD - MM); int t = MM + i % (TPAD - MM);
  Zt[(size_t)bd * TPAD + t] = __float2bfloat16(0.f);
}

// ---------------- hTw init: [d][x] = h*w, single bf16 ----------------
__global__ void k_hTw(const float* __restrict__ h, const float* __restrict__ nw,
                      bf16* __restrict__ hw) {
  int xt = blockIdx.x, b = blockIdx.y; int x0 = xt * 64;
  __shared__ float T[128][67];
  __shared__ float wls[64];
  int tid = threadIdx.x;
  if (tid < 64) wls[tid] = nw[(size_t)b * NN + x0 + tid];
  for (int it = 0; it < 32; ++it) {
    int eid = it * 256 + tid; int x = eid >> 7, d = eid & 127;
    T[d][x] = h[((size_t)b * NN + x0 + x) * DD + d];
  }
  __syncthreads();
  for (int it = 0; it < 32; ++it) {
    int eid = it * 256 + tid; int d = eid >> 6, xl = eid & 63;
    float v = T[d][xl] * wls[xl];
    hw[((size_t)b * DD + d) * NN + x0 + xl] = __float2bfloat16(v);
  }
}

// ---------------- slice (MFMA, no LDS, single-bf16): partialT[b][ck][d][t] ----------------
__global__ void __launch_bounds__(256, 4)
k_slice(const bf16* __restrict__ bT, const bf16* __restrict__ hw,
        float* __restrict__ partialT) {
  int ck = blockIdx.x, tg = blockIdx.y, b = blockIdx.z;
  int kbase = ck * (NN / SKC);   // 512-chunk of x
  int tid = threadIdx.x, w = tid >> 6, lane = tid & 63, lr = lane & 15, lg = lane >> 4;
  const bf16* pA = hw + ((size_t)b * DD + w * 32 + lr) * NN + kbase + lg * 8;
  const bf16* pB = bT + ((size_t)b * TPAD + tg * 64 + lr) * NN + kbase + lg * 8;
  f32x4 acc[8];
  #pragma unroll
  for (int i = 0; i < 8; i++) acc[i] = (f32x4){0.f, 0.f, 0.f, 0.f};
  for (int kc = 0; kc < NN / SKC; kc += 64) {
    bf16x8 aa[2][2], bb[2][4];
    #pragma unroll
    for (int ks2 = 0; ks2 < 2; ++ks2) {
      int ko = kc + ks2 * 32;
      #pragma unroll
      for (int fi = 0; fi < 2; ++fi)
        aa[ks2][fi] = *(const bf16x8*)(pA + (size_t)fi * 16 * NN + ko);
      #pragma unroll
      for (int tc = 0; tc < 4; ++tc)
        bb[ks2][tc] = *(const bf16x8*)(pB + (size_t)tc * 16 * NN + ko);
    }
    #pragma unroll
    for (int ks2 = 0; ks2 < 2; ++ks2)
      #pragma unroll
      for (int fi = 0; fi < 2; ++fi)
        #pragma unroll
        for (int tc = 0; tc < 4; ++tc) {
          int ai = fi * 4 + tc;
          acc[ai] = __builtin_amdgcn_mfma_f32_16x16x32_bf16(aa[ks2][fi], bb[ks2][tc], acc[ai], 0, 0, 0);
        }
  }
  float* pp = partialT + ((size_t)(b * SKC + ck) * DD) * TPAD;
  #pragma unroll
  for (int fi = 0; fi < 2; ++fi)
    #pragma unroll
    for (int tc = 0; tc < 4; ++tc)
      #pragma unroll
      for (int r = 0; r < 4; ++r) {
        int d = w * 32 + fi * 16 + lg * 4 + r;
        int t = tg * 64 + tc * 16 + lr;
        pp[(size_t)d * TPAD + t] = acc[fi * 4 + tc][r];
      }
}

// ---------------- reduce: Z[t][d] = sum_ck partialT[ck][d][t] ----------------
__global__ void k_reduce(const float* __restrict__ partialT, float* __restrict__ Z) {
  int idx = blockIdx.x * 256 + threadIdx.x;
  if (idx >= BB * DD * MM) return;
  int b = idx / (DD * MM); int rem = idx % (DD * MM); int d = rem / MM; int t = rem % MM;
  float s = 0.f;
  #pragma unroll
  for (int ck = 0; ck < SKC; ck++)
    s += partialT[((size_t)(b * SKC + ck) * DD + d) * TPAD + t];
  Z[((size_t)b * MM + t) * DD + d] = s;
}

// ---------------- qkv (fused LN1) ----------------
__global__ void k_qkv(const float* __restrict__ Z, const float* __restrict__ lnw,
                      const float* __restrict__ lnb, const float* __restrict__ W,
                      const float* __restrict__ bias, float* __restrict__ q,
                      float* __restrict__ k, float* __restrict__ v) {
  int row = blockIdx.x;            // b*M + t
  int b = row / MM, t = row % MM;
  int j = threadIdx.x;             // 0..383
  __shared__ float zr[128];
  __shared__ float red[4];
  if (j < 128) {
    float val = Z[(size_t)row * DD + j];
    zr[j] = val;
    float s = val, q2 = val * val;
    for (int off = 32; off; off >>= 1) { s += __shfl_xor(s, off); q2 += __shfl_xor(q2, off); }
    if ((j & 63) == 0) { red[(j >> 6) * 2] = s; red[(j >> 6) * 2 + 1] = q2; }
  }
  __syncthreads();
  float s = red[0] + red[2], q2 = red[1] + red[3];
  float mean = s / 128.f;
  float var = q2 / 128.f - mean * mean;
  float inv = rsqrtf(var + 1e-5f);
  if (j < 128) zr[j] = (zr[j] - mean) * inv * lnw[j] + lnb[j];
  __syncthreads();
  float acc = bias[j];
  for (int i = 0; i < 128; i++) acc += zr[i] * W[(size_t)i * 384 + j];
  int which = j >> 7;
  int jj = j & 127;
  int hh = jj >> 4, dh = jj & 15;
  float* dst = (which == 0) ? q : (which == 1) ? k : v;
  dst[((size_t)(b * HHD + hh) * MM + t) * DHH + dh] = acc;
}

// ---------------- attention (split-KV, 8 segs/row, shfl merge) ----------------
__global__ void __launch_bounds__(256, 4)
k_att(const float* __restrict__ q, const float* __restrict__ k,
      const float* __restrict__ v, float* __restrict__ obuf) {
  int bh = blockIdx.y; int b = bh / HHD, hh = bh % HHD;
  int rt = blockIdx.x;             // 0..8, rows rt*32 .. rt*32+31
  __shared__ float ks[MM * DHH];
  __shared__ float vs[MM * DHH];
  const float* kp = k + (size_t)bh * MM * DHH;
  const float* vp = v + (size_t)bh * MM * DHH;
  for (int i = threadIdx.x; i < MM * DHH; i += 256) { ks[i] = kp[i]; vs[i] = vp[i]; }
  __syncthreads();
  const float scale = 0.25f;
  int tid = threadIdx.x;
  int row = rt * 32 + (tid >> 3);
  int seg = tid & 7;
  float m = -1e30f, s = 0.f, o[16];
  #pragma unroll
  for (int j = 0; j < 16; j++) o[j] = 0.f;
  if (row < MM) {
    float qr[16];
    const float* qp = q + ((size_t)bh * MM + row) * DHH;
    #pragma unroll
    for (int j = 0; j < 16; j++) qr[j] = qp[j];
    int t0 = seg * 33;
    int t1 = t0 + 33; if (t1 > MM) t1 = MM;
    for (int t = t0; t < t1; t++) {
      float sc = 0.f;
      #pragma unroll
      for (int j = 0; j < 16; j++) sc += qr[j] * ks[t * 16 + j];
      sc *= scale;
      float mn = fmaxf(m, sc);
      float corr = __expf(m - mn);
      float e = __expf(sc - mn);
      s = s * corr + e;
      #pragma unroll
      for (int j = 0; j < 16; j++) o[j] = o[j] * corr + e * vs[t * 16 + j];
      m = mn;
    }
  }
  #pragma unroll
  for (int off2 = 1; off2 < 8; off2 <<= 1) {
    float m2 = __shfl_xor(m, off2);
    float s2 = __shfl_xor(s, off2);
    float mn = fmaxf(m, m2);
    float c1 = __expf(m - mn), c2 = __expf(m2 - mn);
    s = s * c1 + s2 * c2;
    #pragma unroll
    for (int j = 0; j < 16; j++) o[j] = o[j] * c1 + __shfl_xor(o[j], off2) * c2;
    m = mn;
  }
  if (seg == 0 && row < MM) {
    float invs = 1.f / s;
    float* op = obuf + ((size_t)(b * MM + row)) * DD + hh * DHH;
    #pragma unroll
    for (int j4 = 0; j4 < 4; ++j4) {
      float4 vv = make_float4(o[j4 * 4] * invs, o[j4 * 4 + 1] * invs,
                              o[j4 * 4 + 2] * invs, o[j4 * 4 + 3] * invs);
      *(float4*)(op + j4 * 4) = vv;
    }
  }
}

// ---------------- attn out proj -> Zt single bf16 (fused zt) ----------------
__global__ void k_ao(const float* __restrict__ obuf, const float* __restrict__ W,
                     const float* __restrict__ bias, const float* __restrict__ Z,
                     bf16* __restrict__ Zt) {
  int row = blockIdx.x; int d = threadIdx.x;
  int b = row / MM, t = row % MM;
  __shared__ float orow[128];
  orow[d] = obuf[(size_t)row * DD + d];
  __syncthreads();
  float acc = bias[d];
  for (int i = 0; i < 128; i++) acc += orow[i] * W[(size_t)i * DD + d];
  float nz = Z[(size_t)row * DD + d] + acc;
  Zt[((size_t)b * DD + d) * TPAD + t] = __float2bfloat16(nz);
}

// ------- deslice (MFMA, pure global, single-bf16 Zt) + fused LN2 -> ln2h -------
__global__ void __launch_bounds__(256, 4)
k_deslice(const bf16* __restrict__ bR, const bf16* __restrict__ Zt,
          const float* __restrict__ lw, const float* __restrict__ lb,
          float* __restrict__ h, bf16* __restrict__ ln2h) {
  int xt = blockIdx.x, b = blockIdx.y;
  int x0 = xt * 64;
  int tid = threadIdx.x, w = tid >> 6, lane = tid & 63, lr = lane & 15, lg = lane >> 4;
  const bf16* pA = bR + ((size_t)b * NN + x0 + w * 16 + lr) * TPAD + lg * 8;
  const bf16* pB = Zt + ((size_t)b * DD + lr) * TPAD + lg * 8;
  f32x4 acc[8];
  #pragma unroll
  for (int i = 0; i < 8; i++) acc[i] = (f32x4){0.f, 0.f, 0.f, 0.f};
  for (int kc = 0; kc < TPAD; kc += 64) {
    #pragma unroll
    for (int ks2 = 0; ks2 < 2; ++ks2) {
      int ko = kc + ks2 * 32;
      bf16x8 a = *(const bf16x8*)(pA + ko);
      bf16x8 bb[8];
      #pragma unroll
      for (int fi = 0; fi < 8; ++fi)
        bb[fi] = *(const bf16x8*)(pB + (size_t)fi * 16 * TPAD + ko);
      #pragma unroll
      for (int fi = 0; fi < 8; ++fi)
        acc[fi] = __builtin_amdgcn_mfma_f32_16x16x32_bf16(a, bb[fi], acc[fi], 0, 0, 0);
    }
  }
  float lwv[8], lbv[8];
  #pragma unroll
  for (int fi = 0; fi < 8; ++fi) { lwv[fi] = lw[fi * 16 + lr]; lbv[fi] = lb[fi * 16 + lr]; }
  float hv[8][4];
  float sm[4], sq[4];
  #pragma unroll
  for (int r = 0; r < 4; ++r) { sm[r] = 0.f; sq[r] = 0.f; }
  size_t rowbase = ((size_t)b * NN + x0 + w * 16 + lg * 4);
  #pragma unroll
  for (int fi = 0; fi < 8; ++fi)
    #pragma unroll
    for (int r = 0; r < 4; ++r) {
      float v = h[(rowbase + r) * DD + fi * 16 + lr] + acc[fi][r];
      hv[fi][r] = v; sm[r] += v; sq[r] += v * v;
    }
  #pragma unroll
  for (int r = 0; r < 4; ++r) {
    float s = sm[r], q = sq[r];
    s += __shfl_xor(s, 1); q += __shfl_xor(q, 1);
    s += __shfl_xor(s, 2); q += __shfl_xor(q, 2);
    s += __shfl_xor(s, 4); q += __shfl_xor(q, 4);
    s += __shfl_xor(s, 8); q += __shfl_xor(q, 8);
    float mean = s / 128.f;
    float var = q / 128.f - mean * mean;
    sm[r] = mean; sq[r] = rsqrtf(var + 1e-5f);
  }
  #pragma unroll
  for (int fi = 0; fi < 8; ++fi)
    #pragma unroll
    for (int r = 0; r < 4; ++r) {
      float v = hv[fi][r];
      h[(rowbase + r) * DD + fi * 16 + lr] = v;
      float ln = (v - sm[r]) * sq[r] * lwv[fi] + lbv[fi];
      ln2h[(rowbase + r) * DD + fi * 16 + lr] = __float2bfloat16(ln);
    }
}

// ------- ffnA (MFMA, 64-row blocks, single-bf16 W): mid = gelu(ln2h @ f1 + b1) -------
__global__ void __launch_bounds__(256, 2)
k_ffnA(const bf16* __restrict__ ln2h, const bf16* __restrict__ f1T,
       const float* __restrict__ b1, bf16* __restrict__ mid) {
  int x0 = blockIdx.x * 64;
  int tid = threadIdx.x, w = tid >> 6, lane = tid & 63, lr = lane & 15, lg = lane >> 4;
  int f0 = w * 128;
  __shared__ short mid_s[16][DFFN + 8];
  f32x4 acc[4][8];
  #pragma unroll
  for (int rt = 0; rt < 4; ++rt)
    #pragma unroll
    for (int fi = 0; fi < 8; ++fi) acc[rt][fi] = (f32x4){0.f, 0.f, 0.f, 0.f};
  #pragma unroll
  for (int ks = 0; ks < 4; ++ks) {
    bf16x8 a[4];
    #pragma unroll
    for (int rt = 0; rt < 4; ++rt)
      a[rt] = *(const bf16x8*)(ln2h + ((size_t)x0 + rt * 16 + lr) * DD + ks * 32 + lg * 8);
    bf16x8 bh[8];
    #pragma unroll
    for (int fi = 0; fi < 8; ++fi)
      bh[fi] = *(const bf16x8*)(f1T + (size_t)(f0 + fi * 16 + lr) * DD + ks * 32 + lg * 8);
    #pragma unroll
    for (int fi = 0; fi < 8; ++fi)
      #pragma unroll
      for (int rt = 0; rt < 4; ++rt)
        acc[rt][fi] = __builtin_amdgcn_mfma_f32_16x16x32_bf16(a[rt], bh[fi], acc[rt][fi], 0, 0, 0);
  }
  #pragma unroll
  for (int rt = 0; rt < 4; ++rt) {
    __syncthreads();
    #pragma unroll
    for (int fi = 0; fi < 8; ++fi) {
      int col = f0 + fi * 16 + lr;
      float bb = b1[col];
      #pragma unroll
      for (int r = 0; r < 4; ++r) {
        float xx = acc[rt][fi][r] + bb;
        float gl = 0.5f * xx * (1.f + erff(xx * 0.70710678118654752f));
        mid_s[lg * 4 + r][col] = b2s(__float2bfloat16(gl));
      }
    }
    __syncthreads();
    #pragma unroll
    for (int it = 0; it < 4; ++it) {
      int eid = it * 256 + tid;
      int row = eid >> 6, c = eid & 63;
      uint4 vv = *(const uint4*)&mid_s[row][c * 8];
      *(uint4*)(mid + ((size_t)x0 + rt * 16 + row) * DFFN + c * 8) = vv;
    }
  }
}

// ------- ffnB (MFMA, single-bf16 W): h += mid@f2 + b2; writes hw -------
__global__ void __launch_bounds__(256, 2)
k_ffnB(const bf16* __restrict__ mid, const bf16* __restrict__ f2T,
       const float* __restrict__ b2, const float* __restrict__ nw,
       float* __restrict__ h, bf16* __restrict__ hw) {
  int x0 = blockIdx.x * 64;
  int b = x0 / NN; int xb = x0 % NN;
  int tid = threadIdx.x, w = tid >> 6, lane = tid & 63, lr = lane & 15, lg = lane >> 4;
  int d0 = w * 32;
  __shared__ float T[128][67];
  __shared__ float wls[64];
  if (tid < 64) wls[tid] = nw[(size_t)b * NN + xb + tid];
  f32x4 acc[4][2];
  #pragma unroll
  for (int rt = 0; rt < 4; ++rt)
    #pragma unroll
    for (int dj = 0; dj < 2; ++dj) acc[rt][dj] = (f32x4){0.f, 0.f, 0.f, 0.f};
  #pragma unroll
  for (int ks = 0; ks < 16; ++ks) {
    bf16x8 a[4];
    #pragma unroll
    for (int rt = 0; rt < 4; ++rt)
      a[rt] = *(const bf16x8*)(mid + ((size_t)x0 + rt * 16 + lr) * DFFN + ks * 32 + lg * 8);
    bf16x8 bh[2];
    #pragma unroll
    for (int dj = 0; dj < 2; ++dj)
      bh[dj] = *(const bf16x8*)(f2T + (size_t)(d0 + dj * 16 + lr) * DFFN + ks * 32 + lg * 8);
    #pragma unroll
    for (int dj = 0; dj < 2; ++dj)
      #pragma unroll
      for (int rt = 0; rt < 4; ++rt)
        acc[rt][dj] = __builtin_amdgcn_mfma_f32_16x16x32_bf16(a[rt], bh[dj], acc[rt][dj], 0, 0, 0);
  }
  #pragma unroll
  for (int dj = 0; dj < 2; ++dj) {
    int d = d0 + dj * 16 + lr;
    float bb = b2[d];
    #pragma unroll
    for (int rt = 0; rt < 4; ++rt)
      #pragma unroll
      for (int r = 0; r < 4; ++r) {
        int rowl = rt * 16 + lg * 4 + r;
        float v = h[((size_t)x0 + rowl) * DD + d] + acc[rt][dj][r] + bb;
        h[((size_t)x0 + rowl) * DD + d] = v;
        T[d][rowl] = v;
      }
  }
  __syncthreads();
  for (int it = 0; it < 32; ++it) {
    int eid = it * 256 + tid; int d = eid >> 6, xl = eid & 63;
    float v = T[d][xl] * wls[xl];
    hw[((size_t)b * DD + d) * NN + xb + xl] = __float2bfloat16(v);
  }
}

// ---------------- final LN + out proj (f32 out) ----------------
__global__ void k_out(const float* __restrict__ h, const float* __restrict__ lw,
                      const float* __restrict__ lb, const float* __restrict__ ow,
                      const float* __restrict__ ob, float* __restrict__ out) {
  int row = blockIdx.x; int tid = threadIdx.x;
  float v = h[(size_t)row * DD + tid];
  float s = v, q = v * v;
  for (int off = 32; off; off >>= 1) { s += __shfl_xor(s, off); q += __shfl_xor(q, off); }
  __shared__ float sh[4];
  __shared__ float sp[4];
  int wv = tid >> 6;
  if ((tid & 63) == 0) { sh[wv] = s; sh[2 + wv] = q; }
  __syncthreads();
  s = sh[0] + sh[1]; q = sh[2] + sh[3];
  float mean = s / 128.f, var = q / 128.f - mean * mean;
  float inv = rsqrtf(var + 1e-5f);
  float ln = (v - mean) * inv * lw[tid] + lb[tid];
  float p0 = ln * ow[tid * 2 + 0], p1 = ln * ow[tid * 2 + 1];
  for (int off = 32; off; off >>= 1) { p0 += __shfl_xor(p0, off); p1 += __shfl_xor(p1, off); }
  if ((tid & 63) == 0) { sp[wv] = p0; sp[2 + wv] = p1; }
  __syncthreads();
  if (tid == 0) out[(size_t)row * 2 + 0] = sp[0] + sp[1] + ob[0];
  if (tid == 1) out[(size_t)row * 2 + 1] = sp[2] + sp[3] + ob[1];
}

extern "C" void kernel_launch(void* const* d_in, const int* in_sizes, int n_in,
                              void* d_out, int out_size, void* d_ws, size_t ws_size,
                              hipStream_t stream) {
  const float* u      = (const float*)d_in[0];
  const float* nodes  = (const float*)d_in[1];
  const float* nw     = (const float*)d_in[2];
  const float* modes  = (const float*)d_in[3];
  const float* coordB = (const float*)d_in[4];
  const float* cp_w   = (const float*)d_in[5];
  const float* cp_b   = (const float*)d_in[6];
  const float* in_w   = (const float*)d_in[7];
  const float* in_b   = (const float*)d_in[8];
  const float* ln1_w  = (const float*)d_in[9];
  const float* ln1_b  = (const float*)d_in[10];
  const float* qkv_w  = (const float*)d_in[11];
  const float* qkv_b  = (const float*)d_in[12];
  const float* ao_w   = (const float*)d_in[13];
  const float* ao_b   = (const float*)d_in[14];
  const float* f1_w   = (const float*)d_in[15];
  const float* f1_b   = (const float*)d_in[16];
  const float* f2_w   = (const float*)d_in[17];
  const float* f2_b   = (const float*)d_in[18];
  const float* ln2_w  = (const float*)d_in[19];
  const float* ln2_b  = (const float*)d_in[20];
  const float* lnf_w  = (const float*)d_in[21];
  const float* lnf_b  = (const float*)d_in[22];
  const float* out_w  = (const float*)d_in[23];
  const float* out_b  = (const float*)d_in[24];

  char* ws = (char*)d_ws;
  size_t off = 0;
  bf16* bT    = (bf16*)(ws + off); off += (size_t)BB * TPAD * NN * 2;   // 41.9 MB
  bf16* bR    = (bf16*)(ws + off); off += (size_t)BB * NN * TPAD * 2;   // 41.9 MB
  float* h    = (float*)(ws + off); off += (size_t)BB * NN * DD * 4;    // 33.6 MB
  bf16* hw    = (bf16*)(ws + off); off += (size_t)BB * DD * NN * 2;     // 16.8 MB
  bf16* ln2h  = (bf16*)(ws + off); off += (size_t)BB * NN * DD * 2;     // 16.8 MB
  char* regMid = ws + off; off += (size_t)BB * NN * DFFN * 2;           // 67.1 MB
  float* partialT = (float*)regMid;                       // live: slice -> reduce
  bf16*  mid      = (bf16*)regMid;                        // live: ffnA -> ffnB
  float* qb  = (float*)(regMid + 40 * 1024 * 1024);       // live: qkv -> att
  float* kb  = qb  + (size_t)BB * MM * DD;
  float* vb  = kb  + (size_t)BB * MM * DD;
  float* ob2 = vb  + (size_t)BB * MM * DD;                // live: att -> ao
  float* Z    = (float*)(ws + off); off += (size_t)BB * MM * DD * 4;
  bf16* Zt    = (bf16*)(ws + off); off += (size_t)BB * DD * TPAD * 2;
  bf16* f1T   = (bf16*)(ws + off); off += (size_t)LL * DFFN * DD * 2;
  bf16* f2T   = (bf16*)(ws + off); off += (size_t)LL * DD * DFFN * 2;
  // total ~214 MB

  k_prepW<<<(2 * LL * DFFN * DD + 255) / 256, 256, 0, stream>>>(f1_w, f2_w, f1T, f2T);
  k_embed<<<BB * NN / 64, 256, 0, stream>>>(u, nodes, coordB, cp_w, cp_b, in_w, in_b, h);
  k_basesT<<<dim3(NN / 256, TPAD, BB), 256, 0, stream>>>(nodes, modes, bT);
  k_basesR<<<BB * NN, TPAD, 0, stream>>>(nodes, modes, bR);
  k_hTw<<<dim3(NN / 64, BB), 256, 0, stream>>>(h, nw, hw);
  k_ztpad<<<(BB * DD * (TPAD - MM) + 255) / 256, 256, 0, stream>>>(Zt);

  for (int l = 0; l < LL; l++) {
    k_slice<<<dim3(SKC, TPAD / 64, BB), 256, 0, stream>>>(bT, hw, partialT);
    k_reduce<<<(BB * DD * MM + 255) / 256, 256, 0, stream>>>(partialT, Z);
    k_qkv<<<BB * MM, 384, 0, stream>>>(Z, ln1_w + l * DD, ln1_b + l * DD,
                                       qkv_w + (size_t)l * DD * 3 * DD, qkv_b + l * 3 * DD, qb, kb, vb);
    k_att<<<dim3(9, BB * HHD), 256, 0, stream>>>(qb, kb, vb, ob2);
    k_ao<<<BB * MM, 128, 0, stream>>>(ob2, ao_w + (size_t)l * DD * DD, ao_b + l * DD, Z, Zt);
    k_deslice<<<dim3(NN / 64, BB), 256, 0, stream>>>(bR, Zt,
                                                     ln2_w + l * DD, ln2_b + l * DD, h, ln2h);
    k_ffnA<<<BB * NN / 64, 256, 0, stream>>>(ln2h, f1T + (size_t)l * DFFN * DD,
                                             f1_b + l * DFFN, mid);
    k_ffnB<<<BB * NN / 64, 256, 0, stream>>>(mid, f2T + (size_t)l * DD * DFFN,
                                             f2_b + l * DD, nw, h, hw);
  }
  k_out<<<BB * NN, 128, 0, stream>>>(h, lnf_w, lnf_b, out_w, out_b, (float*)d_out);
}